// Round 10
// baseline (380.486 us; speedup 1.0000x reference)
//
#include <hip/hip_runtime.h>
#include <hip/hip_bf16.h>
#include <math.h>

#define N_NODES 50000
#define N_EDGES 800000
#define F_IN 512
#define HID 128
#define NCLS 40
#define NBLK 196   // ceil(N_NODES/256)

typedef unsigned short u16;
typedef __attribute__((ext_vector_type(8))) short short8;
typedef __attribute__((ext_vector_type(4))) float f32x4;

__device__ inline u16 f2bf(float f) {
    unsigned int u = __float_as_uint(f);
    unsigned int r = (u + 0x7FFFu + ((u >> 16) & 1u)) >> 16;
    return (u16)r;
}
__device__ inline float bf2f(u16 b) {
    return __uint_as_float(((unsigned int)b) << 16);
}

// ---------------- CSR build ----------------

__global__ void k_zero_deg(int* __restrict__ deg) {
    int i = blockIdx.x * 256 + threadIdx.x;
    if (i < N_NODES) deg[i] = 0;
}

__global__ void k_count(const int* __restrict__ row, int* __restrict__ deg) {
    int e = blockIdx.x * 256 + threadIdx.x;
    if (e < N_EDGES) atomicAdd(&deg[row[e]], 1);
}

__device__ inline int wave_incl_scan(int v, int lane) {
    #pragma unroll
    for (int off = 1; off < 64; off <<= 1) {
        int g = __shfl_up(v, off);
        if (lane >= off) v += g;
    }
    return v;
}

__global__ void k_scan_partial(const int* __restrict__ deg, int* __restrict__ blocksum) {
    int t = threadIdx.x;
    int i = blockIdx.x * 256 + t;
    int v = (i < N_NODES) ? deg[i] : 0;
    #pragma unroll
    for (int off = 32; off; off >>= 1) v += __shfl_xor(v, off);
    __shared__ int ws[4];
    if ((t & 63) == 0) ws[t >> 6] = v;
    __syncthreads();
    if (t == 0) blocksum[blockIdx.x] = ws[0] + ws[1] + ws[2] + ws[3];
}

__global__ void k_scan_block(const int* __restrict__ blocksum, int* __restrict__ blockoff) {
    int t = threadIdx.x, lane = t & 63, w = t >> 6;
    int v = (t < NBLK) ? blocksum[t] : 0;
    int incl = wave_incl_scan(v, lane);
    __shared__ int wsum[4];
    if (lane == 63) wsum[w] = incl;
    __syncthreads();
    int woff = 0;
    for (int j = 0; j < w; ++j) woff += wsum[j];
    incl += woff;
    if (t < NBLK) blockoff[t] = incl - v;
    if (t == NBLK - 1) blockoff[NBLK] = incl;
}

// exclusive scan + rowptr/cursor + dinv (fused)
__global__ void k_scan_final(const int* __restrict__ deg, const int* __restrict__ blockoff,
                             int* __restrict__ rowptr, int* __restrict__ cursor,
                             float* __restrict__ dinv) {
    int t = threadIdx.x, lane = t & 63, w = t >> 6;
    int i = blockIdx.x * 256 + t;
    int d = (i < N_NODES) ? deg[i] : 0;
    int incl = wave_incl_scan(d, lane);
    __shared__ int wsum[4];
    if (lane == 63) wsum[w] = incl;
    __syncthreads();
    int woff = 0;
    for (int j = 0; j < w; ++j) woff += wsum[j];
    int excl = incl - d + woff + blockoff[blockIdx.x];
    if (i < N_NODES) {
        rowptr[i] = excl;
        cursor[i] = excl;
        dinv[i] = rsqrtf((float)(d + 1));   // +1 self-loop
    }
    if (i == 0) rowptr[N_NODES] = blockoff[NBLK];
}

__global__ void k_scatter(const int* __restrict__ row, const int* __restrict__ col,
                          int* __restrict__ cursor, int* __restrict__ csr_col) {
    int e = blockIdx.x * 256 + threadIdx.x;
    if (e >= N_EDGES) return;
    int r = row[e], c = col[e];
    int pos = atomicAdd(&cursor[r], 1);
    __builtin_nontemporal_store(c, &csr_col[pos]);   // bypass L2: kill write-allocate amplification
}

// ---------------- weight split into fragment-major layout ----------------
// W [Kdim][128] f32 -> Whi/Wlo in layout [s][j][ln][h][q]:
//   k = s*32 + h*8 + q, n = j*16 + ln
//   pos = (((s*8 + j)*16 + ln)*32) + h*8 + q

__global__ void k_wsplit(const float* __restrict__ W, u16* __restrict__ Whi,
                         u16* __restrict__ Wlo, int Kdim) {
    int idx = blockIdx.x * 256 + threadIdx.x;
    if (idx >= Kdim * 128) return;
    int k = idx >> 7, n = idx & 127;
    float f = W[idx];
    u16 hb = f2bf(f);
    u16 lb = f2bf(f - bf2f(hb));
    int s = k >> 5, hq = (k >> 3) & 3, q = k & 7;
    int j = n >> 4, lnn = n & 15;
    size_t pos = ((((size_t)s * 8 + j) * 16 + lnn) * 32) + hq * 8 + q;
    Whi[pos] = hb;
    Wlo[pos] = lb;
}

// ---------------- direct MFMA GEMM: no LDS, no barriers, 2-deep pipeline -
// 256 threads = 4 waves; wave owns 32 rows x 128 cols. acc[2][8].
// __launch_bounds__(256,2): ~256-VGPR budget so the whole K-step's loads
// (4 A + 16 B) stay in flight -> one waitcnt per step, not per load.
// Split precision: acc += Ahi*Bhi + Ahi*Blo.

template<int K, bool AF32>
__global__ __launch_bounds__(256, 2) void k_gemm_direct(
    const void* __restrict__ Ap, const u16* __restrict__ Wh,
    const u16* __restrict__ Wl, u16* __restrict__ C, int M)
{
    const int t = threadIdx.x;
    const int w = t >> 6, l = t & 63;
    const int ln = l & 15, h = l >> 4;
    const int r0 = blockIdx.x * 128 + w * 32;
    const float* Af = (const float*)Ap;
    const u16*   Ab = (const u16*)Ap;
    const int nt = K / 32;

    const int ra = r0 + ln;
    const int rb = r0 + 16 + ln;
    const bool va = ra < M, vb = rb < M;
    const float* pa = Af + (size_t)ra * K + h * 8;
    const float* pb = Af + (size_t)rb * K + h * 8;
    const u16*   qa = Ab + (size_t)ra * K + h * 8;
    const u16*   qb = Ab + (size_t)rb * K + h * 8;

    f32x4 acc[2][8];
    #pragma unroll
    for (int i = 0; i < 2; ++i)
        #pragma unroll
        for (int j = 0; j < 8; ++j)
            acc[i][j] = (f32x4){0.f, 0.f, 0.f, 0.f};

    const float4 fz = make_float4(0.f, 0.f, 0.f, 0.f);
    const short8 sz = {0, 0, 0, 0, 0, 0, 0, 0};
    float4 a0c = fz, a1c = fz, b0c = fz, b1c = fz;   // cur A (f32 path)
    float4 a0n = fz, a1n = fz, b0n = fz, b1n = fz;   // next A
    short8 u0c = sz, u1c = sz, u0n = sz, u1n = sz;   // cur/next A (bf16 path)

    // prologue: load A for step 0
    if constexpr (AF32) {
        if (va) { a0c = ((const float4*)pa)[0]; a1c = ((const float4*)pa)[1]; }
        if (vb) { b0c = ((const float4*)pb)[0]; b1c = ((const float4*)pb)[1]; }
    } else {
        if (va) u0c = *(const short8*)qa;
        if (vb) u1c = *(const short8*)qb;
    }

    for (int s = 0; s < nt; ++s) {
        // 1) issue next-step A loads (latency hidden under this step's MFMA)
        if (s + 1 < nt) {
            const int k1 = (s + 1) * 32;
            if constexpr (AF32) {
                if (va) { a0n = ((const float4*)(pa + k1))[0]; a1n = ((const float4*)(pa + k1))[1]; }
                if (vb) { b0n = ((const float4*)(pb + k1))[0]; b1n = ((const float4*)(pb + k1))[1]; }
            } else {
                if (va) u0n = *(const short8*)(qa + k1);
                if (vb) u1n = *(const short8*)(qb + k1);
            }
        }
        // 2) issue ALL B-fragment loads for this step (L2-hot, coalesced)
        short8 bh[8], bl[8];
        #pragma unroll
        for (int j = 0; j < 8; ++j) {
            size_t off = ((((size_t)s * 8 + j) * 16 + ln) * 32) + h * 8;
            bh[j] = *(const short8*)(Wh + off);
            bl[j] = *(const short8*)(Wl + off);
        }
        // 3) convert current A (already resident) while B flies
        short8 ah[2];
        if constexpr (AF32) {
            union { short8 s8; u16 u[8]; } c0, c1;
            c0.u[0] = f2bf(a0c.x); c0.u[1] = f2bf(a0c.y);
            c0.u[2] = f2bf(a0c.z); c0.u[3] = f2bf(a0c.w);
            c0.u[4] = f2bf(a1c.x); c0.u[5] = f2bf(a1c.y);
            c0.u[6] = f2bf(a1c.z); c0.u[7] = f2bf(a1c.w);
            c1.u[0] = f2bf(b0c.x); c1.u[1] = f2bf(b0c.y);
            c1.u[2] = f2bf(b0c.z); c1.u[3] = f2bf(b0c.w);
            c1.u[4] = f2bf(b1c.x); c1.u[5] = f2bf(b1c.y);
            c1.u[6] = f2bf(b1c.z); c1.u[7] = f2bf(b1c.w);
            ah[0] = c0.s8; ah[1] = c1.s8;
        } else {
            ah[0] = u0c; ah[1] = u1c;
        }
        // 4) MFMA
        #pragma unroll
        for (int i = 0; i < 2; ++i)
            #pragma unroll
            for (int j = 0; j < 8; ++j) {
                acc[i][j] = __builtin_amdgcn_mfma_f32_16x16x32_bf16(ah[i], bh[j], acc[i][j], 0, 0, 0);
                acc[i][j] = __builtin_amdgcn_mfma_f32_16x16x32_bf16(ah[i], bl[j], acc[i][j], 0, 0, 0);
            }
        // 5) rotate pipeline registers
        if constexpr (AF32) {
            a0c = a0n; a1c = a1n; b0c = b0n; b1c = b1n;
        } else {
            u0c = u0n; u1c = u1n;
        }
    }

    // epilogue: C[r0 + i*16 + h*4 + v][j*16 + ln] = acc[i][j][v]
    #pragma unroll
    for (int i = 0; i < 2; ++i) {
        #pragma unroll
        for (int v = 0; v < 4; ++v) {
            int gr = r0 + i * 16 + h * 4 + v;
            if (gr < M) {
                #pragma unroll
                for (int j = 0; j < 8; ++j)
                    C[(size_t)gr * 128 + j * 16 + ln] = f2bf(acc[i][j][v]);
            }
        }
    }
}

// ---------------- GEMM: [M x 128] bf16 @ [128 x 40] f32 -> [M x 40] -----

__global__ void k_gemm40(const u16* __restrict__ A, const float* __restrict__ W,
                         float* __restrict__ C, int M) {
    __shared__ float As[64][132];
    __shared__ float Ws[128][40];
    int t = threadIdx.x;
    int row0 = blockIdx.x * 64;
    #pragma unroll
    for (int i = 0; i < 4; ++i) {
        int fidx = t + i * 256;          // 0..1023
        int r = fidx >> 4;               // 0..63
        int c = (fidx & 15) * 8;         // 0..120
        int gr = row0 + r;
        uint4 v = {0, 0, 0, 0};
        if (gr < M) v = *reinterpret_cast<const uint4*>(A + (size_t)gr * 128 + c);
        const u16* pv = (const u16*)&v;
        #pragma unroll
        for (int q = 0; q < 8; ++q) As[r][c + q] = bf2f(pv[q]);
    }
    #pragma unroll
    for (int i = 0; i < 5; ++i) {
        int fidx = t + i * 256;
        int r = fidx / 10, c = (fidx % 10) << 2;
        float4 v = *reinterpret_cast<const float4*>(W + r * 40 + c);
        *reinterpret_cast<float4*>(&Ws[r][c]) = v;
    }
    __syncthreads();
    int r = t >> 2;
    int cg = t & 3;
    float acc[10];
    #pragma unroll
    for (int j = 0; j < 10; ++j) acc[j] = 0.0f;
    for (int k = 0; k < 128; ++k) {
        float a = As[r][k];
        #pragma unroll
        for (int j = 0; j < 10; ++j)
            acc[j] = fmaf(a, Ws[k][cg * 10 + j], acc[j]);
    }
    int gr = row0 + r;
    if (gr < M) {
        #pragma unroll
        for (int j = 0; j < 10; ++j)
            C[(size_t)gr * 40 + cg * 10 + j] = acc[j];
    }
}

// ---------------- CSR aggregation, bf16 h -> relu'd bf16 out (NF=128) ---

__global__ void k_agg_csr_bf(const u16* __restrict__ h, const float* __restrict__ dinv,
                             const float* __restrict__ bias,
                             const int* __restrict__ rowptr, const int* __restrict__ csr_col,
                             u16* __restrict__ out) {
    int gid = blockIdx.x * 256 + threadIdx.x;
    if (gid >= N_NODES * 32) return;
    int i = gid >> 5;
    int q = (gid & 31) * 4;
    float di = dinv[i];
    float s = di * di;
    ushort4 hv = *reinterpret_cast<const ushort4*>(h + (size_t)i * 128 + q);
    float4 bv = *reinterpret_cast<const float4*>(bias + q);
    float4 acc;
    acc.x = fmaf(bf2f(hv.x), s, bv.x);
    acc.y = fmaf(bf2f(hv.y), s, bv.y);
    acc.z = fmaf(bf2f(hv.z), s, bv.z);
    acc.w = fmaf(bf2f(hv.w), s, bv.w);
    int e = rowptr[i], e1 = rowptr[i + 1];
    for (; e + 1 < e1; e += 2) {
        int c0 = csr_col[e], c1 = csr_col[e + 1];
        float n0 = di * dinv[c0], n1 = di * dinv[c1];
        ushort4 v0 = *reinterpret_cast<const ushort4*>(h + (size_t)c0 * 128 + q);
        ushort4 v1 = *reinterpret_cast<const ushort4*>(h + (size_t)c1 * 128 + q);
        acc.x = fmaf(bf2f(v0.x), n0, acc.x);
        acc.y = fmaf(bf2f(v0.y), n0, acc.y);
        acc.z = fmaf(bf2f(v0.z), n0, acc.z);
        acc.w = fmaf(bf2f(v0.w), n0, acc.w);
        acc.x = fmaf(bf2f(v1.x), n1, acc.x);
        acc.y = fmaf(bf2f(v1.y), n1, acc.y);
        acc.z = fmaf(bf2f(v1.z), n1, acc.z);
        acc.w = fmaf(bf2f(v1.w), n1, acc.w);
    }
    if (e < e1) {
        int c0 = csr_col[e];
        float n0 = di * dinv[c0];
        ushort4 v0 = *reinterpret_cast<const ushort4*>(h + (size_t)c0 * 128 + q);
        acc.x = fmaf(bf2f(v0.x), n0, acc.x);
        acc.y = fmaf(bf2f(v0.y), n0, acc.y);
        acc.z = fmaf(bf2f(v0.z), n0, acc.z);
        acc.w = fmaf(bf2f(v0.w), n0, acc.w);
    }
    ushort4 o;
    o.x = f2bf(fmaxf(acc.x, 0.f));
    o.y = f2bf(fmaxf(acc.y, 0.f));
    o.z = f2bf(fmaxf(acc.z, 0.f));
    o.w = f2bf(fmaxf(acc.w, 0.f));
    *reinterpret_cast<ushort4*>(out + (size_t)i * 128 + q) = o;
}

// ---------------- fused layer-3 aggregation + log_softmax ----------------
// One wave per node: lane f (<40) owns feature f; gather over edges, then
// wave-reduce max/sum for log_softmax, write final output.

__global__ void k_agg_ls(const float* __restrict__ h, const float* __restrict__ dinv,
                         const float* __restrict__ bias,
                         const int* __restrict__ rowptr, const int* __restrict__ csr_col,
                         float* __restrict__ out) {
    int wv = threadIdx.x >> 6, lane = threadIdx.x & 63;
    int i = blockIdx.x * 4 + wv;
    if (i >= N_NODES) return;
    int fl = lane < NCLS ? lane : NCLS - 1;   // clamp for safe loads
    float di = dinv[i];
    float acc = h[(size_t)i * NCLS + fl] * di * di + bias[fl];
    int e = rowptr[i], e1 = rowptr[i + 1];
    for (; e < e1; ++e) {
        int c = csr_col[e];
        float nv = di * dinv[c];
        acc = fmaf(h[(size_t)c * NCLS + fl], nv, acc);
    }
    float v = (lane < NCLS) ? acc : -INFINITY;
    float m = v;
    #pragma unroll
    for (int off = 32; off; off >>= 1) m = fmaxf(m, __shfl_xor(m, off));
    float ex = (lane < NCLS) ? expf(v - m) : 0.0f;
    float ssum = ex;
    #pragma unroll
    for (int off = 32; off; off >>= 1) ssum += __shfl_xor(ssum, off);
    float ls = logf(ssum);
    if (lane < NCLS) out[(size_t)i * NCLS + lane] = v - m - ls;
}

// ---------------- launch ----------------

extern "C" void kernel_launch(void* const* d_in, const int* in_sizes, int n_in,
                              void* d_out, int out_size, void* d_ws, size_t ws_size,
                              hipStream_t stream) {
    const float* x  = (const float*)d_in[0];
    const int* ei   = (const int*)d_in[1];
    const float* W1 = (const float*)d_in[2];
    const float* b1 = (const float*)d_in[3];
    const float* W2 = (const float*)d_in[4];
    const float* b2 = (const float*)d_in[5];
    const float* W3 = (const float*)d_in[6];
    const float* b3 = (const float*)d_in[7];
    float* out = (float*)d_out;

    const int* row = ei;             // targets
    const int* col = ei + N_EDGES;   // sources

    char* ws = (char*)d_ws;
    int*   deg      = (int*)ws;   ws += sizeof(int) * N_NODES;
    int*   rowptr   = (int*)ws;   ws += sizeof(int) * 50004;
    int*   cursor   = (int*)ws;   ws += sizeof(int) * N_NODES;
    int*   blocksum = (int*)ws;   ws += sizeof(int) * NBLK;
    int*   blockoff = (int*)ws;   ws += sizeof(int) * 204;
    int*   csr_col  = (int*)ws;   ws += sizeof(int) * N_EDGES;
    float* dinv     = (float*)ws; ws += sizeof(float) * N_NODES;
    u16*   wt1hi    = (u16*)ws;   ws += sizeof(u16) * F_IN * 128;
    u16*   wt1lo    = (u16*)ws;   ws += sizeof(u16) * F_IN * 128;
    u16*   wt2hi    = (u16*)ws;   ws += sizeof(u16) * HID * 128;
    u16*   wt2lo    = (u16*)ws;   ws += sizeof(u16) * HID * 128;
    u16*   hbuf     = (u16*)ws;   ws += sizeof(u16) * (size_t)N_NODES * HID;
    u16*   abuf     = (u16*)ws;   ws += sizeof(u16) * (size_t)N_NODES * HID;
    float* h3       = (float*)ws; ws += sizeof(float) * (size_t)N_NODES * NCLS;

    const int NB_N = (N_NODES + 255) / 256;
    const int NB_E = (N_EDGES + 255) / 256;
    const int NB_G = (N_NODES + 63) / 64;     // for gemm40
    const int NB_D = (N_NODES + 127) / 128;   // for direct gemm

    // weight split (fragment-major, once)
    k_wsplit<<<(F_IN * 128 + 255) / 256, 256, 0, stream>>>(W1, wt1hi, wt1lo, F_IN);
    k_wsplit<<<(HID * 128 + 255) / 256, 256, 0, stream>>>(W2, wt2hi, wt2lo, HID);

    // CSR build (once, shared by all 3 layers)
    k_zero_deg<<<NB_N, 256, 0, stream>>>(deg);
    k_count<<<NB_E, 256, 0, stream>>>(row, deg);
    k_scan_partial<<<NBLK, 256, 0, stream>>>(deg, blocksum);
    k_scan_block<<<1, 256, 0, stream>>>(blocksum, blockoff);
    k_scan_final<<<NBLK, 256, 0, stream>>>(deg, blockoff, rowptr, cursor, dinv);
    k_scatter<<<NB_E, 256, 0, stream>>>(row, col, cursor, csr_col);

    // layer 1: x (f32) @ W1 -> hbuf (bf16)
    k_gemm_direct<F_IN, true><<<NB_D, 256, 0, stream>>>(x, wt1hi, wt1lo, hbuf, N_NODES);
    k_agg_csr_bf<<<(N_NODES * 32 + 255) / 256, 256, 0, stream>>>(
        hbuf, dinv, b1, rowptr, csr_col, abuf);   // -> relu'd bf16

    // layer 2: abuf (bf16) @ W2 -> hbuf (bf16)
    k_gemm_direct<HID, false><<<NB_D, 256, 0, stream>>>(abuf, wt2hi, wt2lo, hbuf, N_NODES);
    k_agg_csr_bf<<<(N_NODES * 32 + 255) / 256, 256, 0, stream>>>(
        hbuf, dinv, b2, rowptr, csr_col, abuf);   // -> relu'd bf16

    // layer 3: abuf (bf16) @ W3 -> h3 (f32), then fused agg + log_softmax
    k_gemm40<<<NB_G, 256, 0, stream>>>(abuf, W3, h3, N_NODES);
    k_agg_ls<<<(N_NODES + 3) / 4, 256, 0, stream>>>(
        h3, dinv, b3, rowptr, csr_col, out);
}

// Round 11
// 333.773 us; speedup vs baseline: 1.1400x; 1.1400x over previous
//
#include <hip/hip_runtime.h>
#include <hip/hip_bf16.h>
#include <math.h>

#define N_NODES 50000
#define N_EDGES 800000
#define F_IN 512
#define HID 128
#define NCLS 40
#define NBLK 196   // ceil(N_NODES/256)

typedef unsigned short u16;
typedef __attribute__((ext_vector_type(8))) short short8;
typedef __attribute__((ext_vector_type(4))) float f32x4;

__device__ inline u16 f2bf(float f) {
    unsigned int u = __float_as_uint(f);
    unsigned int r = (u + 0x7FFFu + ((u >> 16) & 1u)) >> 16;
    return (u16)r;
}
__device__ inline float bf2f(u16 b) {
    return __uint_as_float(((unsigned int)b) << 16);
}

// ---------------- CSR build ----------------

__global__ void k_zero_deg(int* __restrict__ deg) {
    int i = blockIdx.x * 256 + threadIdx.x;
    if (i < N_NODES) deg[i] = 0;
}

__global__ void k_count(const int* __restrict__ row, int* __restrict__ deg) {
    int e = blockIdx.x * 256 + threadIdx.x;
    if (e < N_EDGES) atomicAdd(&deg[row[e]], 1);
}

__device__ inline int wave_incl_scan(int v, int lane) {
    #pragma unroll
    for (int off = 1; off < 64; off <<= 1) {
        int g = __shfl_up(v, off);
        if (lane >= off) v += g;
    }
    return v;
}

__global__ void k_scan_partial(const int* __restrict__ deg, int* __restrict__ blocksum) {
    int t = threadIdx.x;
    int i = blockIdx.x * 256 + t;
    int v = (i < N_NODES) ? deg[i] : 0;
    #pragma unroll
    for (int off = 32; off; off >>= 1) v += __shfl_xor(v, off);
    __shared__ int ws[4];
    if ((t & 63) == 0) ws[t >> 6] = v;
    __syncthreads();
    if (t == 0) blocksum[blockIdx.x] = ws[0] + ws[1] + ws[2] + ws[3];
}

__global__ void k_scan_block(const int* __restrict__ blocksum, int* __restrict__ blockoff) {
    int t = threadIdx.x, lane = t & 63, w = t >> 6;
    int v = (t < NBLK) ? blocksum[t] : 0;
    int incl = wave_incl_scan(v, lane);
    __shared__ int wsum[4];
    if (lane == 63) wsum[w] = incl;
    __syncthreads();
    int woff = 0;
    for (int j = 0; j < w; ++j) woff += wsum[j];
    incl += woff;
    if (t < NBLK) blockoff[t] = incl - v;
    if (t == NBLK - 1) blockoff[NBLK] = incl;
}

// exclusive scan + rowptr/cursor + dinv (fused)
__global__ void k_scan_final(const int* __restrict__ deg, const int* __restrict__ blockoff,
                             int* __restrict__ rowptr, int* __restrict__ cursor,
                             float* __restrict__ dinv) {
    int t = threadIdx.x, lane = t & 63, w = t >> 6;
    int i = blockIdx.x * 256 + t;
    int d = (i < N_NODES) ? deg[i] : 0;
    int incl = wave_incl_scan(d, lane);
    __shared__ int wsum[4];
    if (lane == 63) wsum[w] = incl;
    __syncthreads();
    int woff = 0;
    for (int j = 0; j < w; ++j) woff += wsum[j];
    int excl = incl - d + woff + blockoff[blockIdx.x];
    if (i < N_NODES) {
        rowptr[i] = excl;
        cursor[i] = excl;
        dinv[i] = rsqrtf((float)(d + 1));   // +1 self-loop
    }
    if (i == 0) rowptr[N_NODES] = blockoff[NBLK];
}

__global__ void k_scatter(const int* __restrict__ row, const int* __restrict__ col,
                          int* __restrict__ cursor, int* __restrict__ csr_col) {
    int e = blockIdx.x * 256 + threadIdx.x;
    if (e >= N_EDGES) return;
    int r = row[e], c = col[e];
    int pos = atomicAdd(&cursor[r], 1);
    __builtin_nontemporal_store(c, &csr_col[pos]);   // bypass L2: kill write-allocate amplification
}

// ---------------- weight split into fragment-major layout ----------------
// W [Kdim][128] f32 -> Whi/Wlo in layout [s][j][ln][h][q]:
//   k = s*32 + h*8 + q, n = j*16 + ln
//   pos = (((s*8 + j)*16 + ln)*32) + h*8 + q

__global__ void k_wsplit(const float* __restrict__ W, u16* __restrict__ Whi,
                         u16* __restrict__ Wlo, int Kdim) {
    int idx = blockIdx.x * 256 + threadIdx.x;
    if (idx >= Kdim * 128) return;
    int k = idx >> 7, n = idx & 127;
    float f = W[idx];
    u16 hb = f2bf(f);
    u16 lb = f2bf(f - bf2f(hb));
    int s = k >> 5, hq = (k >> 3) & 3, q = k & 7;
    int j = n >> 4, lnn = n & 15;
    size_t pos = ((((size_t)s * 8 + j) * 16 + lnn) * 32) + hq * 8 + q;
    Whi[pos] = hb;
    Wlo[pos] = lb;
}

// ---------------- direct MFMA GEMM: no LDS, no barriers, 2-deep pipeline -

template<int K, bool AF32>
__global__ __launch_bounds__(256, 2) void k_gemm_direct(
    const void* __restrict__ Ap, const u16* __restrict__ Wh,
    const u16* __restrict__ Wl, u16* __restrict__ C, int M)
{
    const int t = threadIdx.x;
    const int w = t >> 6, l = t & 63;
    const int ln = l & 15, h = l >> 4;
    const int r0 = blockIdx.x * 128 + w * 32;
    const float* Af = (const float*)Ap;
    const u16*   Ab = (const u16*)Ap;
    const int nt = K / 32;

    const int ra = r0 + ln;
    const int rb = r0 + 16 + ln;
    const bool va = ra < M, vb = rb < M;
    const float* pa = Af + (size_t)ra * K + h * 8;
    const float* pb = Af + (size_t)rb * K + h * 8;
    const u16*   qa = Ab + (size_t)ra * K + h * 8;
    const u16*   qb = Ab + (size_t)rb * K + h * 8;

    f32x4 acc[2][8];
    #pragma unroll
    for (int i = 0; i < 2; ++i)
        #pragma unroll
        for (int j = 0; j < 8; ++j)
            acc[i][j] = (f32x4){0.f, 0.f, 0.f, 0.f};

    const float4 fz = make_float4(0.f, 0.f, 0.f, 0.f);
    const short8 sz = {0, 0, 0, 0, 0, 0, 0, 0};
    float4 a0c = fz, a1c = fz, b0c = fz, b1c = fz;
    float4 a0n = fz, a1n = fz, b0n = fz, b1n = fz;
    short8 u0c = sz, u1c = sz, u0n = sz, u1n = sz;

    if constexpr (AF32) {
        if (va) { a0c = ((const float4*)pa)[0]; a1c = ((const float4*)pa)[1]; }
        if (vb) { b0c = ((const float4*)pb)[0]; b1c = ((const float4*)pb)[1]; }
    } else {
        if (va) u0c = *(const short8*)qa;
        if (vb) u1c = *(const short8*)qb;
    }

    for (int s = 0; s < nt; ++s) {
        if (s + 1 < nt) {
            const int k1 = (s + 1) * 32;
            if constexpr (AF32) {
                if (va) { a0n = ((const float4*)(pa + k1))[0]; a1n = ((const float4*)(pa + k1))[1]; }
                if (vb) { b0n = ((const float4*)(pb + k1))[0]; b1n = ((const float4*)(pb + k1))[1]; }
            } else {
                if (va) u0n = *(const short8*)(qa + k1);
                if (vb) u1n = *(const short8*)(qb + k1);
            }
        }
        short8 bh[8], bl[8];
        #pragma unroll
        for (int j = 0; j < 8; ++j) {
            size_t off = ((((size_t)s * 8 + j) * 16 + ln) * 32) + h * 8;
            bh[j] = *(const short8*)(Wh + off);
            bl[j] = *(const short8*)(Wl + off);
        }
        short8 ah[2];
        if constexpr (AF32) {
            union { short8 s8; u16 u[8]; } c0, c1;
            c0.u[0] = f2bf(a0c.x); c0.u[1] = f2bf(a0c.y);
            c0.u[2] = f2bf(a0c.z); c0.u[3] = f2bf(a0c.w);
            c0.u[4] = f2bf(a1c.x); c0.u[5] = f2bf(a1c.y);
            c0.u[6] = f2bf(a1c.z); c0.u[7] = f2bf(a1c.w);
            c1.u[0] = f2bf(b0c.x); c1.u[1] = f2bf(b0c.y);
            c1.u[2] = f2bf(b0c.z); c1.u[3] = f2bf(b0c.w);
            c1.u[4] = f2bf(b1c.x); c1.u[5] = f2bf(b1c.y);
            c1.u[6] = f2bf(b1c.z); c1.u[7] = f2bf(b1c.w);
            ah[0] = c0.s8; ah[1] = c1.s8;
        } else {
            ah[0] = u0c; ah[1] = u1c;
        }
        #pragma unroll
        for (int i = 0; i < 2; ++i)
            #pragma unroll
            for (int j = 0; j < 8; ++j) {
                acc[i][j] = __builtin_amdgcn_mfma_f32_16x16x32_bf16(ah[i], bh[j], acc[i][j], 0, 0, 0);
                acc[i][j] = __builtin_amdgcn_mfma_f32_16x16x32_bf16(ah[i], bl[j], acc[i][j], 0, 0, 0);
            }
        if constexpr (AF32) {
            a0c = a0n; a1c = a1n; b0c = b0n; b1c = b1n;
        } else {
            u0c = u0n; u1c = u1n;
        }
    }

    #pragma unroll
    for (int i = 0; i < 2; ++i) {
        #pragma unroll
        for (int v = 0; v < 4; ++v) {
            int gr = r0 + i * 16 + h * 4 + v;
            if (gr < M) {
                #pragma unroll
                for (int j = 0; j < 8; ++j)
                    C[(size_t)gr * 128 + j * 16 + ln] = f2bf(acc[i][j][v]);
            }
        }
    }
}

// ---------------- GEMM: [M x 128] bf16 @ [128 x 40] f32 -> [M x 40] bf16 -

__global__ void k_gemm40(const u16* __restrict__ A, const float* __restrict__ W,
                         u16* __restrict__ C, int M) {
    __shared__ float As[64][132];
    __shared__ float Ws[128][40];
    int t = threadIdx.x;
    int row0 = blockIdx.x * 64;
    #pragma unroll
    for (int i = 0; i < 4; ++i) {
        int fidx = t + i * 256;          // 0..1023
        int r = fidx >> 4;               // 0..63
        int c = (fidx & 15) * 8;         // 0..120
        int gr = row0 + r;
        uint4 v = {0, 0, 0, 0};
        if (gr < M) v = *reinterpret_cast<const uint4*>(A + (size_t)gr * 128 + c);
        const u16* pv = (const u16*)&v;
        #pragma unroll
        for (int q = 0; q < 8; ++q) As[r][c + q] = bf2f(pv[q]);
    }
    #pragma unroll
    for (int i = 0; i < 5; ++i) {
        int fidx = t + i * 256;
        int r = fidx / 10, c = (fidx % 10) << 2;
        float4 v = *reinterpret_cast<const float4*>(W + r * 40 + c);
        *reinterpret_cast<float4*>(&Ws[r][c]) = v;
    }
    __syncthreads();
    int r = t >> 2;
    int cg = t & 3;
    float acc[10];
    #pragma unroll
    for (int j = 0; j < 10; ++j) acc[j] = 0.0f;
    for (int k = 0; k < 128; ++k) {
        float a = As[r][k];
        #pragma unroll
        for (int j = 0; j < 10; ++j)
            acc[j] = fmaf(a, Ws[k][cg * 10 + j], acc[j]);
    }
    int gr = row0 + r;
    if (gr < M) {
        #pragma unroll
        for (int j = 0; j < 10; ++j)
            C[(size_t)gr * 40 + cg * 10 + j] = f2bf(acc[j]);
    }
}

// ---------------- CSR aggregation, bf16 h -> relu'd bf16 out (NF=128) ---

__global__ void k_agg_csr_bf(const u16* __restrict__ h, const float* __restrict__ dinv,
                             const float* __restrict__ bias,
                             const int* __restrict__ rowptr, const int* __restrict__ csr_col,
                             u16* __restrict__ out) {
    int gid = blockIdx.x * 256 + threadIdx.x;
    if (gid >= N_NODES * 32) return;
    int i = gid >> 5;
    int q = (gid & 31) * 4;
    float di = dinv[i];
    float s = di * di;
    ushort4 hv = *reinterpret_cast<const ushort4*>(h + (size_t)i * 128 + q);
    float4 bv = *reinterpret_cast<const float4*>(bias + q);
    float4 acc;
    acc.x = fmaf(bf2f(hv.x), s, bv.x);
    acc.y = fmaf(bf2f(hv.y), s, bv.y);
    acc.z = fmaf(bf2f(hv.z), s, bv.z);
    acc.w = fmaf(bf2f(hv.w), s, bv.w);
    int e = rowptr[i], e1 = rowptr[i + 1];
    for (; e + 1 < e1; e += 2) {
        int c0 = csr_col[e], c1 = csr_col[e + 1];
        float n0 = di * dinv[c0], n1 = di * dinv[c1];
        ushort4 v0 = *reinterpret_cast<const ushort4*>(h + (size_t)c0 * 128 + q);
        ushort4 v1 = *reinterpret_cast<const ushort4*>(h + (size_t)c1 * 128 + q);
        acc.x = fmaf(bf2f(v0.x), n0, acc.x);
        acc.y = fmaf(bf2f(v0.y), n0, acc.y);
        acc.z = fmaf(bf2f(v0.z), n0, acc.z);
        acc.w = fmaf(bf2f(v0.w), n0, acc.w);
        acc.x = fmaf(bf2f(v1.x), n1, acc.x);
        acc.y = fmaf(bf2f(v1.y), n1, acc.y);
        acc.z = fmaf(bf2f(v1.z), n1, acc.z);
        acc.w = fmaf(bf2f(v1.w), n1, acc.w);
    }
    if (e < e1) {
        int c0 = csr_col[e];
        float n0 = di * dinv[c0];
        ushort4 v0 = *reinterpret_cast<const ushort4*>(h + (size_t)c0 * 128 + q);
        acc.x = fmaf(bf2f(v0.x), n0, acc.x);
        acc.y = fmaf(bf2f(v0.y), n0, acc.y);
        acc.z = fmaf(bf2f(v0.z), n0, acc.z);
        acc.w = fmaf(bf2f(v0.w), n0, acc.w);
    }
    ushort4 o;
    o.x = f2bf(fmaxf(acc.x, 0.f));
    o.y = f2bf(fmaxf(acc.y, 0.f));
    o.z = f2bf(fmaxf(acc.z, 0.f));
    o.w = f2bf(fmaxf(acc.w, 0.f));
    *reinterpret_cast<ushort4*>(out + (size_t)i * 128 + q) = o;
}

// ---------------- CSR aggregation, bf16 h (NF=40, layer 3) -> f32 out ---
// 10 threads/node, each owns 4 features (ushort4 = 8 B gathers).

__global__ void k_agg_csr40_bf(const u16* __restrict__ h, const float* __restrict__ dinv,
                               const float* __restrict__ bias,
                               const int* __restrict__ rowptr, const int* __restrict__ csr_col,
                               float* __restrict__ out) {
    const int TPN = 10;
    int gid = blockIdx.x * 256 + threadIdx.x;
    if (gid >= N_NODES * TPN) return;
    int i = gid / TPN;
    int q = (gid % TPN) * 4;
    float di = dinv[i];
    float s = di * di;
    ushort4 hv = *reinterpret_cast<const ushort4*>(h + (size_t)i * 40 + q);
    float4 bv = *reinterpret_cast<const float4*>(bias + q);
    float4 acc;
    acc.x = fmaf(bf2f(hv.x), s, bv.x);
    acc.y = fmaf(bf2f(hv.y), s, bv.y);
    acc.z = fmaf(bf2f(hv.z), s, bv.z);
    acc.w = fmaf(bf2f(hv.w), s, bv.w);
    int e = rowptr[i], e1 = rowptr[i + 1];
    for (; e + 1 < e1; e += 2) {
        int c0 = csr_col[e], c1 = csr_col[e + 1];
        float n0 = di * dinv[c0], n1 = di * dinv[c1];
        ushort4 v0 = *reinterpret_cast<const ushort4*>(h + (size_t)c0 * 40 + q);
        ushort4 v1 = *reinterpret_cast<const ushort4*>(h + (size_t)c1 * 40 + q);
        acc.x = fmaf(bf2f(v0.x), n0, acc.x);
        acc.y = fmaf(bf2f(v0.y), n0, acc.y);
        acc.z = fmaf(bf2f(v0.z), n0, acc.z);
        acc.w = fmaf(bf2f(v0.w), n0, acc.w);
        acc.x = fmaf(bf2f(v1.x), n1, acc.x);
        acc.y = fmaf(bf2f(v1.y), n1, acc.y);
        acc.z = fmaf(bf2f(v1.z), n1, acc.z);
        acc.w = fmaf(bf2f(v1.w), n1, acc.w);
    }
    if (e < e1) {
        int c0 = csr_col[e];
        float n0 = di * dinv[c0];
        ushort4 v0 = *reinterpret_cast<const ushort4*>(h + (size_t)c0 * 40 + q);
        acc.x = fmaf(bf2f(v0.x), n0, acc.x);
        acc.y = fmaf(bf2f(v0.y), n0, acc.y);
        acc.z = fmaf(bf2f(v0.z), n0, acc.z);
        acc.w = fmaf(bf2f(v0.w), n0, acc.w);
    }
    *reinterpret_cast<float4*>(out + (size_t)i * 40 + q) = acc;
}

// ---------------- log_softmax (in-place, one wave per row) ----------------

__global__ void k_logsoftmax(float* __restrict__ out) {
    int wave = threadIdx.x >> 6, lane = threadIdx.x & 63;
    int rowi = blockIdx.x * 4 + wave;
    if (rowi >= N_NODES) return;
    float v = (lane < NCLS) ? out[(size_t)rowi * NCLS + lane] : -INFINITY;
    float m = v;
    #pragma unroll
    for (int off = 32; off; off >>= 1) m = fmaxf(m, __shfl_xor(m, off));
    float ex = (lane < NCLS) ? expf(v - m) : 0.0f;
    float s = ex;
    #pragma unroll
    for (int off = 32; off; off >>= 1) s += __shfl_xor(s, off);
    float ls = logf(s);
    if (lane < NCLS) out[(size_t)rowi * NCLS + lane] = v - m - ls;
}

// ---------------- launch ----------------

extern "C" void kernel_launch(void* const* d_in, const int* in_sizes, int n_in,
                              void* d_out, int out_size, void* d_ws, size_t ws_size,
                              hipStream_t stream) {
    const float* x  = (const float*)d_in[0];
    const int* ei   = (const int*)d_in[1];
    const float* W1 = (const float*)d_in[2];
    const float* b1 = (const float*)d_in[3];
    const float* W2 = (const float*)d_in[4];
    const float* b2 = (const float*)d_in[5];
    const float* W3 = (const float*)d_in[6];
    const float* b3 = (const float*)d_in[7];
    float* out = (float*)d_out;

    const int* row = ei;             // targets
    const int* col = ei + N_EDGES;   // sources

    char* ws = (char*)d_ws;
    int*   deg      = (int*)ws;   ws += sizeof(int) * N_NODES;
    int*   rowptr   = (int*)ws;   ws += sizeof(int) * 50004;
    int*   cursor   = (int*)ws;   ws += sizeof(int) * N_NODES;
    int*   blocksum = (int*)ws;   ws += sizeof(int) * NBLK;
    int*   blockoff = (int*)ws;   ws += sizeof(int) * 204;
    int*   csr_col  = (int*)ws;   ws += sizeof(int) * N_EDGES;
    float* dinv     = (float*)ws; ws += sizeof(float) * N_NODES;
    u16*   wt1hi    = (u16*)ws;   ws += sizeof(u16) * F_IN * 128;
    u16*   wt1lo    = (u16*)ws;   ws += sizeof(u16) * F_IN * 128;
    u16*   wt2hi    = (u16*)ws;   ws += sizeof(u16) * HID * 128;
    u16*   wt2lo    = (u16*)ws;   ws += sizeof(u16) * HID * 128;
    u16*   hbuf     = (u16*)ws;   ws += sizeof(u16) * (size_t)N_NODES * HID;
    u16*   abuf     = (u16*)ws;   ws += sizeof(u16) * (size_t)N_NODES * HID;
    u16*   h3       = (u16*)ws;   ws += sizeof(u16) * (size_t)N_NODES * NCLS;

    const int NB_N = (N_NODES + 255) / 256;
    const int NB_E = (N_EDGES + 255) / 256;
    const int NB_G = (N_NODES + 63) / 64;     // for gemm40
    const int NB_D = (N_NODES + 127) / 128;   // for direct gemm

    // weight split (fragment-major, once)
    k_wsplit<<<(F_IN * 128 + 255) / 256, 256, 0, stream>>>(W1, wt1hi, wt1lo, F_IN);
    k_wsplit<<<(HID * 128 + 255) / 256, 256, 0, stream>>>(W2, wt2hi, wt2lo, HID);

    // CSR build (once, shared by all 3 layers)
    k_zero_deg<<<NB_N, 256, 0, stream>>>(deg);
    k_count<<<NB_E, 256, 0, stream>>>(row, deg);
    k_scan_partial<<<NBLK, 256, 0, stream>>>(deg, blocksum);
    k_scan_block<<<1, 256, 0, stream>>>(blocksum, blockoff);
    k_scan_final<<<NBLK, 256, 0, stream>>>(deg, blockoff, rowptr, cursor, dinv);
    k_scatter<<<NB_E, 256, 0, stream>>>(row, col, cursor, csr_col);

    // layer 1: x (f32) @ W1 -> hbuf (bf16)
    k_gemm_direct<F_IN, true><<<NB_D, 256, 0, stream>>>(x, wt1hi, wt1lo, hbuf, N_NODES);
    k_agg_csr_bf<<<(N_NODES * 32 + 255) / 256, 256, 0, stream>>>(
        hbuf, dinv, b1, rowptr, csr_col, abuf);   // -> relu'd bf16

    // layer 2: abuf (bf16) @ W2 -> hbuf (bf16)
    k_gemm_direct<HID, false><<<NB_D, 256, 0, stream>>>(abuf, wt2hi, wt2lo, hbuf, N_NODES);
    k_agg_csr_bf<<<(N_NODES * 32 + 255) / 256, 256, 0, stream>>>(
        hbuf, dinv, b2, rowptr, csr_col, abuf);   // -> relu'd bf16

    // layer 3: abuf (bf16) @ W3 -> h3 (bf16), agg -> f32 out, log_softmax
    k_gemm40<<<NB_G, 256, 0, stream>>>(abuf, W3, h3, N_NODES);
    k_agg_csr40_bf<<<(N_NODES * 10 + 255) / 256, 256, 0, stream>>>(
        h3, dinv, b3, rowptr, csr_col, out);
    k_logsoftmax<<<(N_NODES + 3) / 4, 256, 0, stream>>>(out);
}

// Round 12
// 329.746 us; speedup vs baseline: 1.1539x; 1.0122x over previous
//
#include <hip/hip_runtime.h>
#include <hip/hip_bf16.h>
#include <math.h>

#define N_NODES 50000
#define N_EDGES 800000
#define F_IN 512
#define HID 128
#define NCLS 40
#define NBLK 196   // ceil(N_NODES/256)
#define PAD 16     // ints per 64B line (atomic counter padding)

typedef unsigned short u16;
typedef __attribute__((ext_vector_type(8))) short short8;
typedef __attribute__((ext_vector_type(4))) float f32x4;

__device__ inline u16 f2bf(float f) {
    unsigned int u = __float_as_uint(f);
    unsigned int r = (u + 0x7FFFu + ((u >> 16) & 1u)) >> 16;
    return (u16)r;
}
__device__ inline float bf2f(u16 b) {
    return __uint_as_float(((unsigned int)b) << 16);
}

// ---------------- CSR build ----------------

__global__ void k_zero_deg(int* __restrict__ deg) {
    int i = blockIdx.x * 256 + threadIdx.x;
    if (i < N_NODES) deg[(size_t)i * PAD] = 0;
}

__global__ void k_count(const int* __restrict__ row, int* __restrict__ deg) {
    int e = blockIdx.x * 256 + threadIdx.x;
    if (e < N_EDGES) atomicAdd(&deg[(size_t)row[e] * PAD], 1);
}

__device__ inline int wave_incl_scan(int v, int lane) {
    #pragma unroll
    for (int off = 1; off < 64; off <<= 1) {
        int g = __shfl_up(v, off);
        if (lane >= off) v += g;
    }
    return v;
}

__global__ void k_scan_partial(const int* __restrict__ deg, int* __restrict__ blocksum) {
    int t = threadIdx.x;
    int i = blockIdx.x * 256 + t;
    int v = (i < N_NODES) ? deg[(size_t)i * PAD] : 0;
    #pragma unroll
    for (int off = 32; off; off >>= 1) v += __shfl_xor(v, off);
    __shared__ int ws[4];
    if ((t & 63) == 0) ws[t >> 6] = v;
    __syncthreads();
    if (t == 0) blocksum[blockIdx.x] = ws[0] + ws[1] + ws[2] + ws[3];
}

__global__ void k_scan_block(const int* __restrict__ blocksum, int* __restrict__ blockoff) {
    int t = threadIdx.x, lane = t & 63, w = t >> 6;
    int v = (t < NBLK) ? blocksum[t] : 0;
    int incl = wave_incl_scan(v, lane);
    __shared__ int wsum[4];
    if (lane == 63) wsum[w] = incl;
    __syncthreads();
    int woff = 0;
    for (int j = 0; j < w; ++j) woff += wsum[j];
    incl += woff;
    if (t < NBLK) blockoff[t] = incl - v;
    if (t == NBLK - 1) blockoff[NBLK] = incl;
}

// exclusive scan + rowptr/cursor + dinv (fused); cursor padded
__global__ void k_scan_final(const int* __restrict__ deg, const int* __restrict__ blockoff,
                             int* __restrict__ rowptr, int* __restrict__ cursor,
                             float* __restrict__ dinv) {
    int t = threadIdx.x, lane = t & 63, w = t >> 6;
    int i = blockIdx.x * 256 + t;
    int d = (i < N_NODES) ? deg[(size_t)i * PAD] : 0;
    int incl = wave_incl_scan(d, lane);
    __shared__ int wsum[4];
    if (lane == 63) wsum[w] = incl;
    __syncthreads();
    int woff = 0;
    for (int j = 0; j < w; ++j) woff += wsum[j];
    int excl = incl - d + woff + blockoff[blockIdx.x];
    if (i < N_NODES) {
        rowptr[i] = excl;
        cursor[(size_t)i * PAD] = excl;
        dinv[i] = rsqrtf((float)(d + 1));   // +1 self-loop
    }
    if (i == 0) rowptr[N_NODES] = blockoff[NBLK];
}

__global__ void k_scatter(const int* __restrict__ row, const int* __restrict__ col,
                          int* __restrict__ cursor, int* __restrict__ csr_col) {
    int e = blockIdx.x * 256 + threadIdx.x;
    if (e >= N_EDGES) return;
    int r = row[e], c = col[e];
    int pos = atomicAdd(&cursor[(size_t)r * PAD], 1);
    __builtin_nontemporal_store(c, &csr_col[pos]);
}

// ---------------- weight split into fragment-major bf16 (hi only) --------
// W [Kdim][128] f32 -> Whi layout [s][j][ln][h][q]:
//   k = s*32 + h*8 + q, n = j*16 + ln
//   pos = (((s*8 + j)*16 + ln)*32) + h*8 + q

__global__ void k_wsplit(const float* __restrict__ W, u16* __restrict__ Whi, int Kdim) {
    int idx = blockIdx.x * 256 + threadIdx.x;
    if (idx >= Kdim * 128) return;
    int k = idx >> 7, n = idx & 127;
    u16 hb = f2bf(W[idx]);
    int s = k >> 5, hq = (k >> 3) & 3, q = k & 7;
    int j = n >> 4, lnn = n & 15;
    size_t pos = ((((size_t)s * 8 + j) * 16 + lnn) * 32) + hq * 8 + q;
    Whi[pos] = hb;
}

// ---------------- direct MFMA GEMM: no LDS, no barriers ------------------
// 256 threads = 4 waves; each wave owns 16 rows x 128 cols (acc[8]).
// Grid = M/64 blocks -> 2x the waves of the 32-row variant (TLP is the
// latency-hiding mechanism). Single-term bf16: acc += Ahi*Bhi.

template<int K, bool AF32>
__global__ __launch_bounds__(256, 2) void k_gemm_direct(
    const void* __restrict__ Ap, const u16* __restrict__ Wh,
    u16* __restrict__ C, int M)
{
    const int t = threadIdx.x;
    const int w = t >> 6, l = t & 63;
    const int ln = l & 15, h = l >> 4;
    const int r0w = blockIdx.x * 64 + w * 16;
    const int ra = r0w + ln;
    const bool va = ra < M;
    const int nt = K / 32;
    const float* pa = (const float*)Ap + (size_t)ra * K + h * 8;
    const u16*   qa = (const u16*)Ap + (size_t)ra * K + h * 8;

    f32x4 acc[8];
    #pragma unroll
    for (int j = 0; j < 8; ++j) acc[j] = (f32x4){0.f, 0.f, 0.f, 0.f};

    const float4 fz = make_float4(0.f, 0.f, 0.f, 0.f);
    const short8 sz = {0, 0, 0, 0, 0, 0, 0, 0};
    float4 a0c = fz, a1c = fz, a0n = fz, a1n = fz;
    short8 u0c = sz, u0n = sz;

    if constexpr (AF32) {
        if (va) { a0c = ((const float4*)pa)[0]; a1c = ((const float4*)pa)[1]; }
    } else {
        if (va) u0c = *(const short8*)qa;
    }

    for (int s = 0; s < nt; ++s) {
        // prefetch next-step A (HBM latency hides under this step)
        if (s + 1 < nt) {
            const int k1 = (s + 1) * 32;
            if constexpr (AF32) {
                if (va) { a0n = ((const float4*)(pa + k1))[0]; a1n = ((const float4*)(pa + k1))[1]; }
            } else {
                if (va) u0n = *(const short8*)(qa + k1);
            }
        }
        // all 8 B-fragment loads for this step (L2-hot, 1KB/load coalesced)
        short8 bh[8];
        #pragma unroll
        for (int j = 0; j < 8; ++j) {
            size_t off = ((((size_t)s * 8 + j) * 16 + ln) * 32) + h * 8;
            bh[j] = *(const short8*)(Wh + off);
        }
        // current A (already resident) -> bf16 fragment
        short8 ah;
        if constexpr (AF32) {
            union { short8 s8; u16 u[8]; } cv;
            cv.u[0] = f2bf(a0c.x); cv.u[1] = f2bf(a0c.y);
            cv.u[2] = f2bf(a0c.z); cv.u[3] = f2bf(a0c.w);
            cv.u[4] = f2bf(a1c.x); cv.u[5] = f2bf(a1c.y);
            cv.u[6] = f2bf(a1c.z); cv.u[7] = f2bf(a1c.w);
            ah = cv.s8;
        } else {
            ah = u0c;
        }
        #pragma unroll
        for (int j = 0; j < 8; ++j)
            acc[j] = __builtin_amdgcn_mfma_f32_16x16x32_bf16(ah, bh[j], acc[j], 0, 0, 0);
        if constexpr (AF32) { a0c = a0n; a1c = a1n; }
        else { u0c = u0n; }
    }

    // epilogue: C[r0w + h*4 + v][j*16 + ln]
    #pragma unroll
    for (int v = 0; v < 4; ++v) {
        int gr = r0w + h * 4 + v;
        if (gr < M) {
            #pragma unroll
            for (int j = 0; j < 8; ++j)
                C[(size_t)gr * 128 + j * 16 + ln] = f2bf(acc[j][v]);
        }
    }
}

// ---------------- GEMM: [M x 128] bf16 @ [128 x 40] f32 -> [M x 40] bf16 -

__global__ void k_gemm40(const u16* __restrict__ A, const float* __restrict__ W,
                         u16* __restrict__ C, int M) {
    __shared__ float As[64][132];
    __shared__ float Ws[128][40];
    int t = threadIdx.x;
    int row0 = blockIdx.x * 64;
    #pragma unroll
    for (int i = 0; i < 4; ++i) {
        int fidx = t + i * 256;          // 0..1023
        int r = fidx >> 4;               // 0..63
        int c = (fidx & 15) * 8;         // 0..120
        int gr = row0 + r;
        uint4 v = {0, 0, 0, 0};
        if (gr < M) v = *reinterpret_cast<const uint4*>(A + (size_t)gr * 128 + c);
        const u16* pv = (const u16*)&v;
        #pragma unroll
        for (int q = 0; q < 8; ++q) As[r][c + q] = bf2f(pv[q]);
    }
    #pragma unroll
    for (int i = 0; i < 5; ++i) {
        int fidx = t + i * 256;
        int r = fidx / 10, c = (fidx % 10) << 2;
        float4 v = *reinterpret_cast<const float4*>(W + r * 40 + c);
        *reinterpret_cast<float4*>(&Ws[r][c]) = v;
    }
    __syncthreads();
    int r = t >> 2;
    int cg = t & 3;
    float acc[10];
    #pragma unroll
    for (int j = 0; j < 10; ++j) acc[j] = 0.0f;
    for (int k = 0; k < 128; ++k) {
        float a = As[r][k];
        #pragma unroll
        for (int j = 0; j < 10; ++j)
            acc[j] = fmaf(a, Ws[k][cg * 10 + j], acc[j]);
    }
    int gr = row0 + r;
    if (gr < M) {
        #pragma unroll
        for (int j = 0; j < 10; ++j)
            C[(size_t)gr * 40 + cg * 10 + j] = f2bf(acc[j]);
    }
}

// ---------------- CSR aggregation, bf16 h -> relu'd bf16 out (NF=128) ---

__global__ void k_agg_csr_bf(const u16* __restrict__ h, const float* __restrict__ dinv,
                             const float* __restrict__ bias,
                             const int* __restrict__ rowptr, const int* __restrict__ csr_col,
                             u16* __restrict__ out) {
    int gid = blockIdx.x * 256 + threadIdx.x;
    if (gid >= N_NODES * 32) return;
    int i = gid >> 5;
    int q = (gid & 31) * 4;
    float di = dinv[i];
    float s = di * di;
    ushort4 hv = *reinterpret_cast<const ushort4*>(h + (size_t)i * 128 + q);
    float4 bv = *reinterpret_cast<const float4*>(bias + q);
    float4 acc;
    acc.x = fmaf(bf2f(hv.x), s, bv.x);
    acc.y = fmaf(bf2f(hv.y), s, bv.y);
    acc.z = fmaf(bf2f(hv.z), s, bv.z);
    acc.w = fmaf(bf2f(hv.w), s, bv.w);
    int e = rowptr[i], e1 = rowptr[i + 1];
    for (; e + 1 < e1; e += 2) {
        int c0 = csr_col[e], c1 = csr_col[e + 1];
        float n0 = di * dinv[c0], n1 = di * dinv[c1];
        ushort4 v0 = *reinterpret_cast<const ushort4*>(h + (size_t)c0 * 128 + q);
        ushort4 v1 = *reinterpret_cast<const ushort4*>(h + (size_t)c1 * 128 + q);
        acc.x = fmaf(bf2f(v0.x), n0, acc.x);
        acc.y = fmaf(bf2f(v0.y), n0, acc.y);
        acc.z = fmaf(bf2f(v0.z), n0, acc.z);
        acc.w = fmaf(bf2f(v0.w), n0, acc.w);
        acc.x = fmaf(bf2f(v1.x), n1, acc.x);
        acc.y = fmaf(bf2f(v1.y), n1, acc.y);
        acc.z = fmaf(bf2f(v1.z), n1, acc.z);
        acc.w = fmaf(bf2f(v1.w), n1, acc.w);
    }
    if (e < e1) {
        int c0 = csr_col[e];
        float n0 = di * dinv[c0];
        ushort4 v0 = *reinterpret_cast<const ushort4*>(h + (size_t)c0 * 128 + q);
        acc.x = fmaf(bf2f(v0.x), n0, acc.x);
        acc.y = fmaf(bf2f(v0.y), n0, acc.y);
        acc.z = fmaf(bf2f(v0.z), n0, acc.z);
        acc.w = fmaf(bf2f(v0.w), n0, acc.w);
    }
    ushort4 o;
    o.x = f2bf(fmaxf(acc.x, 0.f));
    o.y = f2bf(fmaxf(acc.y, 0.f));
    o.z = f2bf(fmaxf(acc.z, 0.f));
    o.w = f2bf(fmaxf(acc.w, 0.f));
    *reinterpret_cast<ushort4*>(out + (size_t)i * 128 + q) = o;
}

// ---------------- CSR aggregation, bf16 h (NF=40, layer 3) -> f32 out ---

__global__ void k_agg_csr40_bf(const u16* __restrict__ h, const float* __restrict__ dinv,
                               const float* __restrict__ bias,
                               const int* __restrict__ rowptr, const int* __restrict__ csr_col,
                               float* __restrict__ out) {
    const int TPN = 10;
    int gid = blockIdx.x * 256 + threadIdx.x;
    if (gid >= N_NODES * TPN) return;
    int i = gid / TPN;
    int q = (gid % TPN) * 4;
    float di = dinv[i];
    float s = di * di;
    ushort4 hv = *reinterpret_cast<const ushort4*>(h + (size_t)i * 40 + q);
    float4 bv = *reinterpret_cast<const float4*>(bias + q);
    float4 acc;
    acc.x = fmaf(bf2f(hv.x), s, bv.x);
    acc.y = fmaf(bf2f(hv.y), s, bv.y);
    acc.z = fmaf(bf2f(hv.z), s, bv.z);
    acc.w = fmaf(bf2f(hv.w), s, bv.w);
    int e = rowptr[i], e1 = rowptr[i + 1];
    for (; e + 1 < e1; e += 2) {
        int c0 = csr_col[e], c1 = csr_col[e + 1];
        float n0 = di * dinv[c0], n1 = di * dinv[c1];
        ushort4 v0 = *reinterpret_cast<const ushort4*>(h + (size_t)c0 * 40 + q);
        ushort4 v1 = *reinterpret_cast<const ushort4*>(h + (size_t)c1 * 40 + q);
        acc.x = fmaf(bf2f(v0.x), n0, acc.x);
        acc.y = fmaf(bf2f(v0.y), n0, acc.y);
        acc.z = fmaf(bf2f(v0.z), n0, acc.z);
        acc.w = fmaf(bf2f(v0.w), n0, acc.w);
        acc.x = fmaf(bf2f(v1.x), n1, acc.x);
        acc.y = fmaf(bf2f(v1.y), n1, acc.y);
        acc.z = fmaf(bf2f(v1.z), n1, acc.z);
        acc.w = fmaf(bf2f(v1.w), n1, acc.w);
    }
    if (e < e1) {
        int c0 = csr_col[e];
        float n0 = di * dinv[c0];
        ushort4 v0 = *reinterpret_cast<const ushort4*>(h + (size_t)c0 * 40 + q);
        acc.x = fmaf(bf2f(v0.x), n0, acc.x);
        acc.y = fmaf(bf2f(v0.y), n0, acc.y);
        acc.z = fmaf(bf2f(v0.z), n0, acc.z);
        acc.w = fmaf(bf2f(v0.w), n0, acc.w);
    }
    *reinterpret_cast<float4*>(out + (size_t)i * 40 + q) = acc;
}

// ---------------- log_softmax (in-place, one wave per row) ----------------

__global__ void k_logsoftmax(float* __restrict__ out) {
    int wave = threadIdx.x >> 6, lane = threadIdx.x & 63;
    int rowi = blockIdx.x * 4 + wave;
    if (rowi >= N_NODES) return;
    float v = (lane < NCLS) ? out[(size_t)rowi * NCLS + lane] : -INFINITY;
    float m = v;
    #pragma unroll
    for (int off = 32; off; off >>= 1) m = fmaxf(m, __shfl_xor(m, off));
    float ex = (lane < NCLS) ? expf(v - m) : 0.0f;
    float s = ex;
    #pragma unroll
    for (int off = 32; off; off >>= 1) s += __shfl_xor(s, off);
    float ls = logf(s);
    if (lane < NCLS) out[(size_t)rowi * NCLS + lane] = v - m - ls;
}

// ---------------- launch ----------------

extern "C" void kernel_launch(void* const* d_in, const int* in_sizes, int n_in,
                              void* d_out, int out_size, void* d_ws, size_t ws_size,
                              hipStream_t stream) {
    const float* x  = (const float*)d_in[0];
    const int* ei   = (const int*)d_in[1];
    const float* W1 = (const float*)d_in[2];
    const float* b1 = (const float*)d_in[3];
    const float* W2 = (const float*)d_in[4];
    const float* b2 = (const float*)d_in[5];
    const float* W3 = (const float*)d_in[6];
    const float* b3 = (const float*)d_in[7];
    float* out = (float*)d_out;

    const int* row = ei;             // targets
    const int* col = ei + N_EDGES;   // sources

    char* ws = (char*)d_ws;
    int*   deg      = (int*)ws;   ws += sizeof(int) * (size_t)N_NODES * PAD;
    int*   cursor   = (int*)ws;   ws += sizeof(int) * (size_t)N_NODES * PAD;
    int*   rowptr   = (int*)ws;   ws += sizeof(int) * 50004;
    int*   blocksum = (int*)ws;   ws += sizeof(int) * NBLK;
    int*   blockoff = (int*)ws;   ws += sizeof(int) * 204;
    int*   csr_col  = (int*)ws;   ws += sizeof(int) * N_EDGES;
    float* dinv     = (float*)ws; ws += sizeof(float) * N_NODES;
    u16*   wt1hi    = (u16*)ws;   ws += sizeof(u16) * F_IN * 128;
    u16*   wt2hi    = (u16*)ws;   ws += sizeof(u16) * HID * 128;
    u16*   hbuf     = (u16*)ws;   ws += sizeof(u16) * (size_t)N_NODES * HID;
    u16*   abuf     = (u16*)ws;   ws += sizeof(u16) * (size_t)N_NODES * HID;
    u16*   h3       = (u16*)ws;   ws += sizeof(u16) * (size_t)N_NODES * NCLS;

    const int NB_N = (N_NODES + 255) / 256;
    const int NB_E = (N_EDGES + 255) / 256;
    const int NB_G = (N_NODES + 63) / 64;     // for gemm40 and gemm_direct

    // weight split (fragment-major, once)
    k_wsplit<<<(F_IN * 128 + 255) / 256, 256, 0, stream>>>(W1, wt1hi, F_IN);
    k_wsplit<<<(HID * 128 + 255) / 256, 256, 0, stream>>>(W2, wt2hi, HID);

    // CSR build (once, shared by all 3 layers)
    k_zero_deg<<<NB_N, 256, 0, stream>>>(deg);
    k_count<<<NB_E, 256, 0, stream>>>(row, deg);
    k_scan_partial<<<NBLK, 256, 0, stream>>>(deg, blocksum);
    k_scan_block<<<1, 256, 0, stream>>>(blocksum, blockoff);
    k_scan_final<<<NBLK, 256, 0, stream>>>(deg, blockoff, rowptr, cursor, dinv);
    k_scatter<<<NB_E, 256, 0, stream>>>(row, col, cursor, csr_col);

    // layer 1: x (f32) @ W1 -> hbuf (bf16)
    k_gemm_direct<F_IN, true><<<NB_G, 256, 0, stream>>>(x, wt1hi, hbuf, N_NODES);
    k_agg_csr_bf<<<(N_NODES * 32 + 255) / 256, 256, 0, stream>>>(
        hbuf, dinv, b1, rowptr, csr_col, abuf);   // -> relu'd bf16

    // layer 2: abuf (bf16) @ W2 -> hbuf (bf16)
    k_gemm_direct<HID, false><<<NB_G, 256, 0, stream>>>(abuf, wt2hi, hbuf, N_NODES);
    k_agg_csr_bf<<<(N_NODES * 32 + 255) / 256, 256, 0, stream>>>(
        hbuf, dinv, b2, rowptr, csr_col, abuf);   // -> relu'd bf16

    // layer 3: abuf (bf16) @ W3 -> h3 (bf16), agg -> f32 out, log_softmax
    k_gemm40<<<NB_G, 256, 0, stream>>>(abuf, W3, h3, N_NODES);
    k_agg_csr40_bf<<<(N_NODES * 10 + 255) / 256, 256, 0, stream>>>(
        h3, dinv, b3, rowptr, csr_col, out);
    k_logsoftmax<<<(N_NODES + 3) / 4, 256, 0, stream>>>(out);
}

// Round 13
// 311.262 us; speedup vs baseline: 1.2224x; 1.0594x over previous
//
#include <hip/hip_runtime.h>
#include <hip/hip_bf16.h>
#include <math.h>

#define N_NODES 50000
#define N_EDGES 800000
#define F_IN 512
#define HID 128
#define NCLS 40
#define NBLK 196   // ceil(N_NODES/256)
#define PAD 16     // ints per 64B line (atomic counter padding)
#define NBIN 8
#define BIN_SZ 6250  // N_NODES / NBIN

typedef unsigned short u16;
typedef __attribute__((ext_vector_type(8))) short short8;
typedef __attribute__((ext_vector_type(4))) float f32x4;

__device__ inline u16 f2bf(float f) {
    unsigned int u = __float_as_uint(f);
    unsigned int r = (u + 0x7FFFu + ((u >> 16) & 1u)) >> 16;
    return (u16)r;
}
__device__ inline float bf2f(u16 b) {
    return __uint_as_float(((unsigned int)b) << 16);
}

// ---------------- CSR build ----------------

__global__ void k_zero_deg(int* __restrict__ deg) {
    int i = blockIdx.x * 256 + threadIdx.x;
    if (i < N_NODES) deg[(size_t)i * PAD] = 0;
}

// XCD-binned degree count: blocks with blockIdx&7==p handle nodes in
// [p*BIN_SZ,(p+1)*BIN_SZ) -> deg region (400KB) stays in one XCD's L2.
__global__ void k_count_bin(const int* __restrict__ row, int* __restrict__ deg) {
    int bin = blockIdx.x & 7;
    int gblk = blockIdx.x >> 3;
    int nblk = gridDim.x >> 3;
    int lo = bin * BIN_SZ, hi = lo + BIN_SZ;
    for (int e = gblk * 256 + threadIdx.x; e < N_EDGES; e += nblk * 256) {
        int r = row[e];
        if (r >= lo && r < hi) atomicAdd(&deg[(size_t)r * PAD], 1);
    }
}

__device__ inline int wave_incl_scan(int v, int lane) {
    #pragma unroll
    for (int off = 1; off < 64; off <<= 1) {
        int g = __shfl_up(v, off);
        if (lane >= off) v += g;
    }
    return v;
}

__global__ void k_scan_partial(const int* __restrict__ deg, int* __restrict__ blocksum) {
    int t = threadIdx.x;
    int i = blockIdx.x * 256 + t;
    int v = (i < N_NODES) ? deg[(size_t)i * PAD] : 0;
    #pragma unroll
    for (int off = 32; off; off >>= 1) v += __shfl_xor(v, off);
    __shared__ int ws[4];
    if ((t & 63) == 0) ws[t >> 6] = v;
    __syncthreads();
    if (t == 0) blocksum[blockIdx.x] = ws[0] + ws[1] + ws[2] + ws[3];
}

__global__ void k_scan_block(const int* __restrict__ blocksum, int* __restrict__ blockoff) {
    int t = threadIdx.x, lane = t & 63, w = t >> 6;
    int v = (t < NBLK) ? blocksum[t] : 0;
    int incl = wave_incl_scan(v, lane);
    __shared__ int wsum[4];
    if (lane == 63) wsum[w] = incl;
    __syncthreads();
    int woff = 0;
    for (int j = 0; j < w; ++j) woff += wsum[j];
    incl += woff;
    if (t < NBLK) blockoff[t] = incl - v;
    if (t == NBLK - 1) blockoff[NBLK] = incl;
}

// exclusive scan + rowptr/cursor + dinv (fused); cursor padded
__global__ void k_scan_final(const int* __restrict__ deg, const int* __restrict__ blockoff,
                             int* __restrict__ rowptr, int* __restrict__ cursor,
                             float* __restrict__ dinv) {
    int t = threadIdx.x, lane = t & 63, w = t >> 6;
    int i = blockIdx.x * 256 + t;
    int d = (i < N_NODES) ? deg[(size_t)i * PAD] : 0;
    int incl = wave_incl_scan(d, lane);
    __shared__ int wsum[4];
    if (lane == 63) wsum[w] = incl;
    __syncthreads();
    int woff = 0;
    for (int j = 0; j < w; ++j) woff += wsum[j];
    int excl = incl - d + woff + blockoff[blockIdx.x];
    if (i < N_NODES) {
        rowptr[i] = excl;
        cursor[(size_t)i * PAD] = excl;
        dinv[i] = rsqrtf((float)(d + 1));   // +1 self-loop
    }
    if (i == 0) rowptr[N_NODES] = blockoff[NBLK];
}

// XCD-binned scatter: bin's csr_col slice + cursor slice live in one
// XCD's L2; stores are L2-absorbed (16 stores/line merge before writeback).
__global__ void k_scatter_bin(const int* __restrict__ row, const int* __restrict__ col,
                              int* __restrict__ cursor, int* __restrict__ csr_col) {
    int bin = blockIdx.x & 7;
    int gblk = blockIdx.x >> 3;
    int nblk = gridDim.x >> 3;
    int lo = bin * BIN_SZ, hi = lo + BIN_SZ;
    for (int e = gblk * 256 + threadIdx.x; e < N_EDGES; e += nblk * 256) {
        int r = row[e];
        if (r >= lo && r < hi) {
            int pos = atomicAdd(&cursor[(size_t)r * PAD], 1);
            csr_col[pos] = col[e];
        }
    }
}

// ---------------- weight split into fragment-major bf16 (hi only) --------
// W [Kdim][128] f32 -> Whi layout [s][j][ln][h][q]:
//   k = s*32 + h*8 + q, n = j*16 + ln
//   pos = (((s*8 + j)*16 + ln)*32) + h*8 + q

__global__ void k_wsplit(const float* __restrict__ W, u16* __restrict__ Whi, int Kdim) {
    int idx = blockIdx.x * 256 + threadIdx.x;
    if (idx >= Kdim * 128) return;
    int k = idx >> 7, n = idx & 127;
    u16 hb = f2bf(W[idx]);
    int s = k >> 5, hq = (k >> 3) & 3, q = k & 7;
    int j = n >> 4, lnn = n & 15;
    size_t pos = ((((size_t)s * 8 + j) * 16 + lnn) * 32) + hq * 8 + q;
    Whi[pos] = hb;
}

// ---------------- direct MFMA GEMM: register pipeline, depth-matched -----
// 256 threads = 4 waves; wave owns 16 rows x 128 cols (acc[8] in AGPRs).
// A ring depth 4 (covers HBM latency ~4 steps), B ring depth 2 (covers L2
// latency); inner 4-step unroll keeps all ring indices compile-time.
// sched_barrier(0) pins loads above the MFMA block (no convoy re-sinking).

template<int K, bool AF32>
__global__ __launch_bounds__(256) void k_gemm_direct(
    const void* __restrict__ Ap, const u16* __restrict__ Wh,
    u16* __restrict__ C, int M)
{
    const int t = threadIdx.x;
    const int w = t >> 6, l = t & 63;
    const int ln = l & 15, h = l >> 4;
    const int r0w = blockIdx.x * 64 + w * 16;
    const int ra = r0w + ln;
    const bool va = ra < M;
    const int nt = K / 32;   // 16 (K=512) or 4 (K=128); divisible by 4
    const float* pa = (const float*)Ap + (size_t)ra * K + h * 8;
    const u16*   qa = (const u16*)Ap + (size_t)ra * K + h * 8;

    const float4 fz = make_float4(0.f, 0.f, 0.f, 0.f);
    const short8 sz = {0, 0, 0, 0, 0, 0, 0, 0};

    f32x4 acc[8];
    #pragma unroll
    for (int j = 0; j < 8; ++j) acc[j] = (f32x4){0.f, 0.f, 0.f, 0.f};

    float4 af0[4], af1[4];   // A ring (f32 path)
    short8 ub[4];            // A ring (bf16 path)
    short8 bh[2][8];         // B ring

    // prologue: A for steps 0..3, B for step 0
    #pragma unroll
    for (int u = 0; u < 4; ++u) {
        const int ks = u * 32;
        const bool ok = va && (u < nt);
        if constexpr (AF32) {
            af0[u] = ok ? ((const float4*)(pa + ks))[0] : fz;
            af1[u] = ok ? ((const float4*)(pa + ks))[1] : fz;
        } else {
            ub[u] = ok ? *(const short8*)(qa + ks) : sz;
        }
    }
    #pragma unroll
    for (int j = 0; j < 8; ++j) {
        size_t off = (((size_t)j * 16 + ln) * 32) + h * 8;
        bh[0][j] = *(const short8*)(Wh + off);
    }

    for (int m = 0; m < nt / 4; ++m) {
        #pragma unroll
        for (int u = 0; u < 4; ++u) {
            const int s = m * 4 + u;
            // consume A ring slot u -> bf16 fragment
            short8 ah;
            if constexpr (AF32) {
                union { short8 s8; u16 uu[8]; } cv;
                cv.uu[0] = f2bf(af0[u].x); cv.uu[1] = f2bf(af0[u].y);
                cv.uu[2] = f2bf(af0[u].z); cv.uu[3] = f2bf(af0[u].w);
                cv.uu[4] = f2bf(af1[u].x); cv.uu[5] = f2bf(af1[u].y);
                cv.uu[6] = f2bf(af1[u].z); cv.uu[7] = f2bf(af1[u].w);
                ah = cv.s8;
            } else {
                ah = ub[u];
            }
            // refill A ring slot u with step s+4
            {
                const int ks = (s + 4) * 32;
                const bool ok = va && (s + 4 < nt);
                if constexpr (AF32) {
                    if (ok) { af0[u] = ((const float4*)(pa + ks))[0];
                              af1[u] = ((const float4*)(pa + ks))[1]; }
                } else {
                    if (ok) ub[u] = *(const short8*)(qa + ks);
                }
            }
            // issue B for step s+1 into the other ring half
            if (s + 1 < nt) {
                #pragma unroll
                for (int j = 0; j < 8; ++j) {
                    size_t off = ((((size_t)(s + 1) * 8 + j) * 16 + ln) * 32) + h * 8;
                    bh[(u + 1) & 1][j] = *(const short8*)(Wh + off);
                }
            }
            __builtin_amdgcn_sched_barrier(0);   // loads stay above MFMAs
            #pragma unroll
            for (int j = 0; j < 8; ++j)
                acc[j] = __builtin_amdgcn_mfma_f32_16x16x32_bf16(ah, bh[u & 1][j], acc[j], 0, 0, 0);
        }
    }

    // epilogue: C[r0w + h*4 + v][j*16 + ln]
    #pragma unroll
    for (int v = 0; v < 4; ++v) {
        int gr = r0w + h * 4 + v;
        if (gr < M) {
            #pragma unroll
            for (int j = 0; j < 8; ++j)
                C[(size_t)gr * 128 + j * 16 + ln] = f2bf(acc[j][v]);
        }
    }
}

// ---------------- GEMM: [M x 128] bf16 @ [128 x 40] f32 -> [M x 40] bf16 -

__global__ void k_gemm40(const u16* __restrict__ A, const float* __restrict__ W,
                         u16* __restrict__ C, int M) {
    __shared__ float As[64][132];
    __shared__ float Ws[128][40];
    int t = threadIdx.x;
    int row0 = blockIdx.x * 64;
    #pragma unroll
    for (int i = 0; i < 4; ++i) {
        int fidx = t + i * 256;          // 0..1023
        int r = fidx >> 4;               // 0..63
        int c = (fidx & 15) * 8;         // 0..120
        int gr = row0 + r;
        uint4 v = {0, 0, 0, 0};
        if (gr < M) v = *reinterpret_cast<const uint4*>(A + (size_t)gr * 128 + c);
        const u16* pv = (const u16*)&v;
        #pragma unroll
        for (int q = 0; q < 8; ++q) As[r][c + q] = bf2f(pv[q]);
    }
    #pragma unroll
    for (int i = 0; i < 5; ++i) {
        int fidx = t + i * 256;
        int r = fidx / 10, c = (fidx % 10) << 2;
        float4 v = *reinterpret_cast<const float4*>(W + r * 40 + c);
        *reinterpret_cast<float4*>(&Ws[r][c]) = v;
    }
    __syncthreads();
    int r = t >> 2;
    int cg = t & 3;
    float acc[10];
    #pragma unroll
    for (int j = 0; j < 10; ++j) acc[j] = 0.0f;
    for (int k = 0; k < 128; ++k) {
        float a = As[r][k];
        #pragma unroll
        for (int j = 0; j < 10; ++j)
            acc[j] = fmaf(a, Ws[k][cg * 10 + j], acc[j]);
    }
    int gr = row0 + r;
    if (gr < M) {
        #pragma unroll
        for (int j = 0; j < 10; ++j)
            C[(size_t)gr * 40 + cg * 10 + j] = f2bf(acc[j]);
    }
}

// ---------------- CSR aggregation, bf16 h -> relu'd bf16 out (NF=128) ---

__global__ void k_agg_csr_bf(const u16* __restrict__ h, const float* __restrict__ dinv,
                             const float* __restrict__ bias,
                             const int* __restrict__ rowptr, const int* __restrict__ csr_col,
                             u16* __restrict__ out) {
    int gid = blockIdx.x * 256 + threadIdx.x;
    if (gid >= N_NODES * 32) return;
    int i = gid >> 5;
    int q = (gid & 31) * 4;
    float di = dinv[i];
    float s = di * di;
    ushort4 hv = *reinterpret_cast<const ushort4*>(h + (size_t)i * 128 + q);
    float4 bv = *reinterpret_cast<const float4*>(bias + q);
    float4 acc;
    acc.x = fmaf(bf2f(hv.x), s, bv.x);
    acc.y = fmaf(bf2f(hv.y), s, bv.y);
    acc.z = fmaf(bf2f(hv.z), s, bv.z);
    acc.w = fmaf(bf2f(hv.w), s, bv.w);
    int e = rowptr[i], e1 = rowptr[i + 1];
    for (; e + 1 < e1; e += 2) {
        int c0 = csr_col[e], c1 = csr_col[e + 1];
        float n0 = di * dinv[c0], n1 = di * dinv[c1];
        ushort4 v0 = *reinterpret_cast<const ushort4*>(h + (size_t)c0 * 128 + q);
        ushort4 v1 = *reinterpret_cast<const ushort4*>(h + (size_t)c1 * 128 + q);
        acc.x = fmaf(bf2f(v0.x), n0, acc.x);
        acc.y = fmaf(bf2f(v0.y), n0, acc.y);
        acc.z = fmaf(bf2f(v0.z), n0, acc.z);
        acc.w = fmaf(bf2f(v0.w), n0, acc.w);
        acc.x = fmaf(bf2f(v1.x), n1, acc.x);
        acc.y = fmaf(bf2f(v1.y), n1, acc.y);
        acc.z = fmaf(bf2f(v1.z), n1, acc.z);
        acc.w = fmaf(bf2f(v1.w), n1, acc.w);
    }
    if (e < e1) {
        int c0 = csr_col[e];
        float n0 = di * dinv[c0];
        ushort4 v0 = *reinterpret_cast<const ushort4*>(h + (size_t)c0 * 128 + q);
        acc.x = fmaf(bf2f(v0.x), n0, acc.x);
        acc.y = fmaf(bf2f(v0.y), n0, acc.y);
        acc.z = fmaf(bf2f(v0.z), n0, acc.z);
        acc.w = fmaf(bf2f(v0.w), n0, acc.w);
    }
    ushort4 o;
    o.x = f2bf(fmaxf(acc.x, 0.f));
    o.y = f2bf(fmaxf(acc.y, 0.f));
    o.z = f2bf(fmaxf(acc.z, 0.f));
    o.w = f2bf(fmaxf(acc.w, 0.f));
    *reinterpret_cast<ushort4*>(out + (size_t)i * 128 + q) = o;
}

// ---------------- CSR aggregation, bf16 h (NF=40, layer 3) -> f32 out ---

__global__ void k_agg_csr40_bf(const u16* __restrict__ h, const float* __restrict__ dinv,
                               const float* __restrict__ bias,
                               const int* __restrict__ rowptr, const int* __restrict__ csr_col,
                               float* __restrict__ out) {
    const int TPN = 10;
    int gid = blockIdx.x * 256 + threadIdx.x;
    if (gid >= N_NODES * TPN) return;
    int i = gid / TPN;
    int q = (gid % TPN) * 4;
    float di = dinv[i];
    float s = di * di;
    ushort4 hv = *reinterpret_cast<const ushort4*>(h + (size_t)i * 40 + q);
    float4 bv = *reinterpret_cast<const float4*>(bias + q);
    float4 acc;
    acc.x = fmaf(bf2f(hv.x), s, bv.x);
    acc.y = fmaf(bf2f(hv.y), s, bv.y);
    acc.z = fmaf(bf2f(hv.z), s, bv.z);
    acc.w = fmaf(bf2f(hv.w), s, bv.w);
    int e = rowptr[i], e1 = rowptr[i + 1];
    for (; e + 1 < e1; e += 2) {
        int c0 = csr_col[e], c1 = csr_col[e + 1];
        float n0 = di * dinv[c0], n1 = di * dinv[c1];
        ushort4 v0 = *reinterpret_cast<const ushort4*>(h + (size_t)c0 * 40 + q);
        ushort4 v1 = *reinterpret_cast<const ushort4*>(h + (size_t)c1 * 40 + q);
        acc.x = fmaf(bf2f(v0.x), n0, acc.x);
        acc.y = fmaf(bf2f(v0.y), n0, acc.y);
        acc.z = fmaf(bf2f(v0.z), n0, acc.z);
        acc.w = fmaf(bf2f(v0.w), n0, acc.w);
        acc.x = fmaf(bf2f(v1.x), n1, acc.x);
        acc.y = fmaf(bf2f(v1.y), n1, acc.y);
        acc.z = fmaf(bf2f(v1.z), n1, acc.z);
        acc.w = fmaf(bf2f(v1.w), n1, acc.w);
    }
    if (e < e1) {
        int c0 = csr_col[e];
        float n0 = di * dinv[c0];
        ushort4 v0 = *reinterpret_cast<const ushort4*>(h + (size_t)c0 * 40 + q);
        acc.x = fmaf(bf2f(v0.x), n0, acc.x);
        acc.y = fmaf(bf2f(v0.y), n0, acc.y);
        acc.z = fmaf(bf2f(v0.z), n0, acc.z);
        acc.w = fmaf(bf2f(v0.w), n0, acc.w);
    }
    *reinterpret_cast<float4*>(out + (size_t)i * 40 + q) = acc;
}

// ---------------- log_softmax (in-place, one wave per row) ----------------

__global__ void k_logsoftmax(float* __restrict__ out) {
    int wave = threadIdx.x >> 6, lane = threadIdx.x & 63;
    int rowi = blockIdx.x * 4 + wave;
    if (rowi >= N_NODES) return;
    float v = (lane < NCLS) ? out[(size_t)rowi * NCLS + lane] : -INFINITY;
    float m = v;
    #pragma unroll
    for (int off = 32; off; off >>= 1) m = fmaxf(m, __shfl_xor(m, off));
    float ex = (lane < NCLS) ? expf(v - m) : 0.0f;
    float s = ex;
    #pragma unroll
    for (int off = 32; off; off >>= 1) s += __shfl_xor(s, off);
    float ls = logf(s);
    if (lane < NCLS) out[(size_t)rowi * NCLS + lane] = v - m - ls;
}

// ---------------- launch ----------------

extern "C" void kernel_launch(void* const* d_in, const int* in_sizes, int n_in,
                              void* d_out, int out_size, void* d_ws, size_t ws_size,
                              hipStream_t stream) {
    const float* x  = (const float*)d_in[0];
    const int* ei   = (const int*)d_in[1];
    const float* W1 = (const float*)d_in[2];
    const float* b1 = (const float*)d_in[3];
    const float* W2 = (const float*)d_in[4];
    const float* b2 = (const float*)d_in[5];
    const float* W3 = (const float*)d_in[6];
    const float* b3 = (const float*)d_in[7];
    float* out = (float*)d_out;

    const int* row = ei;             // targets
    const int* col = ei + N_EDGES;   // sources

    char* ws = (char*)d_ws;
    int*   deg      = (int*)ws;   ws += sizeof(int) * (size_t)N_NODES * PAD;
    int*   cursor   = (int*)ws;   ws += sizeof(int) * (size_t)N_NODES * PAD;
    int*   rowptr   = (int*)ws;   ws += sizeof(int) * 50004;
    int*   blocksum = (int*)ws;   ws += sizeof(int) * NBLK;
    int*   blockoff = (int*)ws;   ws += sizeof(int) * 204;
    int*   csr_col  = (int*)ws;   ws += sizeof(int) * N_EDGES;
    float* dinv     = (float*)ws; ws += sizeof(float) * N_NODES;
    u16*   wt1hi    = (u16*)ws;   ws += sizeof(u16) * F_IN * 128;
    u16*   wt2hi    = (u16*)ws;   ws += sizeof(u16) * HID * 128;
    u16*   hbuf     = (u16*)ws;   ws += sizeof(u16) * (size_t)N_NODES * HID;
    u16*   abuf     = (u16*)ws;   ws += sizeof(u16) * (size_t)N_NODES * HID;
    u16*   h3       = (u16*)ws;   ws += sizeof(u16) * (size_t)N_NODES * NCLS;

    const int NB_N = (N_NODES + 255) / 256;
    const int NB_G = (N_NODES + 63) / 64;     // for gemm40 and gemm_direct
    const int NB_BIN = 2048;                  // 256 blocks per bin x 8 bins

    // weight split (fragment-major, once)
    k_wsplit<<<(F_IN * 128 + 255) / 256, 256, 0, stream>>>(W1, wt1hi, F_IN);
    k_wsplit<<<(HID * 128 + 255) / 256, 256, 0, stream>>>(W2, wt2hi, HID);

    // CSR build (once, shared by all 3 layers) — XCD-binned count/scatter
    k_zero_deg<<<NB_N, 256, 0, stream>>>(deg);
    k_count_bin<<<NB_BIN, 256, 0, stream>>>(row, deg);
    k_scan_partial<<<NBLK, 256, 0, stream>>>(deg, blocksum);
    k_scan_block<<<1, 256, 0, stream>>>(blocksum, blockoff);
    k_scan_final<<<NBLK, 256, 0, stream>>>(deg, blockoff, rowptr, cursor, dinv);
    k_scatter_bin<<<NB_BIN, 256, 0, stream>>>(row, col, cursor, csr_col);

    // layer 1: x (f32) @ W1 -> hbuf (bf16)
    k_gemm_direct<F_IN, true><<<NB_G, 256, 0, stream>>>(x, wt1hi, hbuf, N_NODES);
    k_agg_csr_bf<<<(N_NODES * 32 + 255) / 256, 256, 0, stream>>>(
        hbuf, dinv, b1, rowptr, csr_col, abuf);   // -> relu'd bf16

    // layer 2: abuf (bf16) @ W2 -> hbuf (bf16)
    k_gemm_direct<HID, false><<<NB_G, 256, 0, stream>>>(abuf, wt2hi, hbuf, N_NODES);
    k_agg_csr_bf<<<(N_NODES * 32 + 255) / 256, 256, 0, stream>>>(
        hbuf, dinv, b2, rowptr, csr_col, abuf);   // -> relu'd bf16

    // layer 3: abuf (bf16) @ W3 -> h3 (bf16), agg -> f32 out, log_softmax
    k_gemm40<<<NB_G, 256, 0, stream>>>(abuf, W3, h3, N_NODES);
    k_agg_csr40_bf<<<(N_NODES * 10 + 255) / 256, 256, 0, stream>>>(
        h3, dinv, b3, rowptr, csr_col, out);
    k_logsoftmax<<<(N_NODES + 3) / 4, 256, 0, stream>>>(out);
}

// Round 14
// 294.842 us; speedup vs baseline: 1.2905x; 1.0557x over previous
//
#include <hip/hip_runtime.h>
#include <hip/hip_bf16.h>
#include <math.h>

#define N_NODES 50000
#define N_EDGES 800000
#define F_IN 512
#define HID 128
#define NCLS 40
#define NBLK 196   // ceil(N_NODES/256)
#define PAD 16     // ints per 64B line (atomic counter padding)
#define NBIN 8
#define BIN_SZ 6250  // N_NODES / NBIN

typedef unsigned short u16;
typedef __attribute__((ext_vector_type(8))) short short8;
typedef __attribute__((ext_vector_type(4))) float f32x4;

__device__ inline u16 f2bf(float f) {
    unsigned int u = __float_as_uint(f);
    unsigned int r = (u + 0x7FFFu + ((u >> 16) & 1u)) >> 16;
    return (u16)r;
}
__device__ inline float bf2f(u16 b) {
    return __uint_as_float(((unsigned int)b) << 16);
}

// ---------------- CSR build ----------------

__global__ void k_zero_deg(int* __restrict__ deg) {
    int i = blockIdx.x * 256 + threadIdx.x;
    if (i < N_NODES) deg[(size_t)i * PAD] = 0;
}

// XCD-binned degree count
__global__ void k_count_bin(const int* __restrict__ row, int* __restrict__ deg) {
    int bin = blockIdx.x & 7;
    int gblk = blockIdx.x >> 3;
    int nblk = gridDim.x >> 3;
    int lo = bin * BIN_SZ, hi = lo + BIN_SZ;
    for (int e = gblk * 256 + threadIdx.x; e < N_EDGES; e += nblk * 256) {
        int r = row[e];
        if (r >= lo && r < hi) atomicAdd(&deg[(size_t)r * PAD], 1);
    }
}

__device__ inline int wave_incl_scan(int v, int lane) {
    #pragma unroll
    for (int off = 1; off < 64; off <<= 1) {
        int g = __shfl_up(v, off);
        if (lane >= off) v += g;
    }
    return v;
}

__global__ void k_scan_partial(const int* __restrict__ deg, int* __restrict__ blocksum) {
    int t = threadIdx.x;
    int i = blockIdx.x * 256 + t;
    int v = (i < N_NODES) ? deg[(size_t)i * PAD] : 0;
    #pragma unroll
    for (int off = 32; off; off >>= 1) v += __shfl_xor(v, off);
    __shared__ int ws[4];
    if ((t & 63) == 0) ws[t >> 6] = v;
    __syncthreads();
    if (t == 0) blocksum[blockIdx.x] = ws[0] + ws[1] + ws[2] + ws[3];
}

__global__ void k_scan_block(const int* __restrict__ blocksum, int* __restrict__ blockoff) {
    int t = threadIdx.x, lane = t & 63, w = t >> 6;
    int v = (t < NBLK) ? blocksum[t] : 0;
    int incl = wave_incl_scan(v, lane);
    __shared__ int wsum[4];
    if (lane == 63) wsum[w] = incl;
    __syncthreads();
    int woff = 0;
    for (int j = 0; j < w; ++j) woff += wsum[j];
    incl += woff;
    if (t < NBLK) blockoff[t] = incl - v;
    if (t == NBLK - 1) blockoff[NBLK] = incl;
}

__global__ void k_scan_final(const int* __restrict__ deg, const int* __restrict__ blockoff,
                             int* __restrict__ rowptr, int* __restrict__ cursor,
                             float* __restrict__ dinv) {
    int t = threadIdx.x, lane = t & 63, w = t >> 6;
    int i = blockIdx.x * 256 + t;
    int d = (i < N_NODES) ? deg[(size_t)i * PAD] : 0;
    int incl = wave_incl_scan(d, lane);
    __shared__ int wsum[4];
    if (lane == 63) wsum[w] = incl;
    __syncthreads();
    int woff = 0;
    for (int j = 0; j < w; ++j) woff += wsum[j];
    int excl = incl - d + woff + blockoff[blockIdx.x];
    if (i < N_NODES) {
        rowptr[i] = excl;
        cursor[(size_t)i * PAD] = excl;
        dinv[i] = rsqrtf((float)(d + 1));   // +1 self-loop
    }
    if (i == 0) rowptr[N_NODES] = blockoff[NBLK];
}

// XCD-binned scatter
__global__ void k_scatter_bin(const int* __restrict__ row, const int* __restrict__ col,
                              int* __restrict__ cursor, int* __restrict__ csr_col) {
    int bin = blockIdx.x & 7;
    int gblk = blockIdx.x >> 3;
    int nblk = gridDim.x >> 3;
    int lo = bin * BIN_SZ, hi = lo + BIN_SZ;
    for (int e = gblk * 256 + threadIdx.x; e < N_EDGES; e += nblk * 256) {
        int r = row[e];
        if (r >= lo && r < hi) {
            int pos = atomicAdd(&cursor[(size_t)r * PAD], 1);
            csr_col[pos] = col[e];
        }
    }
}

// ---------------- weight split into fragment-major bf16 (hi only) --------
// pos = (((s*8 + j)*16 + ln)*32) + h*8 + q ;  k = s*32 + h*8 + q, n = j*16 + ln

__global__ void k_wsplit(const float* __restrict__ W, u16* __restrict__ Whi, int Kdim) {
    int idx = blockIdx.x * 256 + threadIdx.x;
    if (idx >= Kdim * 128) return;
    int k = idx >> 7, n = idx & 127;
    u16 hb = f2bf(W[idx]);
    int s = k >> 5, hq = (k >> 3) & 3, q = k & 7;
    int j = n >> 4, lnn = n & 15;
    size_t pos = ((((size_t)s * 8 + j) * 16 + lnn) * 32) + hq * 8 + q;
    Whi[pos] = hb;
}

// ---------------- MFMA GEMM with global_load_lds A-staging ---------------
// 256 threads = 4 waves; tile 64 rows x 128 cols; wave owns 16 rows.
// BK=64 double-buffered LDS; A staged via global_load_lds (zero VGPR cost,
// vmcnt-queued, drained once per chunk by __syncthreads — m97 pattern).
// LDS read swizzle: byte ^= ((row&7)<<5) [f32] / <<4 [bf16]; the DMA dest
// is linear so the *global source* is inverse-swizzled (rule #21).

template<int K, bool AF32>
__global__ __launch_bounds__(256) void k_gemm_lds(
    const void* __restrict__ Ap, const u16* __restrict__ Wh,
    u16* __restrict__ C, int M)
{
    constexpr int NC = K / 64;                       // chunks of BK=64
    constexpr int CH_BYTES = AF32 ? 16384 : 8192;    // 64 rows x 64 elems
    __shared__ unsigned char sA[2][CH_BYTES];

    const int t = threadIdx.x;
    const int w = t >> 6, l = t & 63;
    const int ln = l & 15, h = l >> 4;
    const int row0 = blockIdx.x * 64;
    const int r0w = row0 + w * 16;

    f32x4 acc[8];
    #pragma unroll
    for (int j = 0; j < 8; ++j) acc[j] = (f32x4){0.f, 0.f, 0.f, 0.f};

    auto stage = [&](int c, int buf) {
        if constexpr (AF32) {
            const float* X = (const float*)Ap;
            #pragma unroll
            for (int i = 0; i < 4; ++i) {
                int srow = row0 + i * 16 + w * 4 + (l >> 4);
                if (srow > M - 1) srow = M - 1;                 // clamp (unused rows)
                int scol = ((l & 15) * 4) ^ ((((w & 1) << 2) + (l >> 4)) << 3);
                const float* gp = X + (size_t)srow * K + c * 64 + scol;
                unsigned char* lp = &sA[buf][i * 4096 + w * 1024];
                __builtin_amdgcn_global_load_lds(
                    (const __attribute__((address_space(1))) void*)gp,
                    (__attribute__((address_space(3))) void*)lp, 16, 0, 0);
            }
        } else {
            const u16* X = (const u16*)Ap;
            #pragma unroll
            for (int i = 0; i < 2; ++i) {
                int srow = row0 + i * 32 + w * 8 + (l >> 3);
                if (srow > M - 1) srow = M - 1;
                int scol = ((l & 7) * 8) ^ ((l >> 3) << 3);
                const u16* gp = X + (size_t)srow * K + c * 64 + scol;
                unsigned char* lp = &sA[buf][i * 4096 + w * 1024];
                __builtin_amdgcn_global_load_lds(
                    (const __attribute__((address_space(1))) void*)gp,
                    (__attribute__((address_space(3))) void*)lp, 16, 0, 0);
            }
        }
    };

    stage(0, 0);
    __syncthreads();   // drains chunk-0 DMA

    int buf = 0;
    for (int c = 0; c < NC; ++c) {
        // B fragments for the chunk's two K-steps (L2-hot, coalesced 1KB/load)
        short8 bh0[8], bh1[8];
        const int s0 = c * 2, s1 = c * 2 + 1;
        #pragma unroll
        for (int j = 0; j < 8; ++j) {
            size_t o0 = ((((size_t)s0 * 8 + j) * 16 + ln) * 32) + h * 8;
            size_t o1 = ((((size_t)s1 * 8 + j) * 16 + ln) * 32) + h * 8;
            bh0[j] = *(const short8*)(Wh + o0);
            bh1[j] = *(const short8*)(Wh + o1);
        }
        // prefetch next chunk's A into the other LDS buffer (DMA, no VGPRs)
        if (c + 1 < NC) stage(c + 1, buf ^ 1);

        // A fragments from LDS (swizzled reads; 2-way bank alias max = free)
        short8 ah0, ah1;
        if constexpr (AF32) {
            const int rb = (w * 16 + ln) * 256;
            const int sw = (ln & 7) << 5;
            float4 p00 = *(const float4*)&sA[buf][rb + ((h * 32) ^ sw)];
            float4 p01 = *(const float4*)&sA[buf][rb + (((h * 32) ^ sw) + 16)];
            float4 p10 = *(const float4*)&sA[buf][rb + ((128 + h * 32) ^ sw)];
            float4 p11 = *(const float4*)&sA[buf][rb + (((128 + h * 32) ^ sw) + 16)];
            union { short8 s8; u16 u[8]; } c0, c1;
            c0.u[0] = f2bf(p00.x); c0.u[1] = f2bf(p00.y);
            c0.u[2] = f2bf(p00.z); c0.u[3] = f2bf(p00.w);
            c0.u[4] = f2bf(p01.x); c0.u[5] = f2bf(p01.y);
            c0.u[6] = f2bf(p01.z); c0.u[7] = f2bf(p01.w);
            c1.u[0] = f2bf(p10.x); c1.u[1] = f2bf(p10.y);
            c1.u[2] = f2bf(p10.z); c1.u[3] = f2bf(p10.w);
            c1.u[4] = f2bf(p11.x); c1.u[5] = f2bf(p11.y);
            c1.u[6] = f2bf(p11.z); c1.u[7] = f2bf(p11.w);
            ah0 = c0.s8; ah1 = c1.s8;
        } else {
            const int rb = (w * 16 + ln) * 128;
            const int sw = (ln & 7) << 4;
            ah0 = *(const short8*)&sA[buf][rb + ((h * 16) ^ sw)];
            ah1 = *(const short8*)&sA[buf][rb + ((64 + h * 16) ^ sw)];
        }

        #pragma unroll
        for (int j = 0; j < 8; ++j)
            acc[j] = __builtin_amdgcn_mfma_f32_16x16x32_bf16(ah0, bh0[j], acc[j], 0, 0, 0);
        #pragma unroll
        for (int j = 0; j < 8; ++j)
            acc[j] = __builtin_amdgcn_mfma_f32_16x16x32_bf16(ah1, bh1[j], acc[j], 0, 0, 0);

        __syncthreads();   // drains next-chunk DMA + protects buffer swap
        buf ^= 1;
    }

    // epilogue: C[r0w + h*4 + v][j*16 + ln]
    #pragma unroll
    for (int v = 0; v < 4; ++v) {
        int gr = r0w + h * 4 + v;
        if (gr < M) {
            #pragma unroll
            for (int j = 0; j < 8; ++j)
                C[(size_t)gr * 128 + j * 16 + ln] = f2bf(acc[j][v]);
        }
    }
}

// ---------------- GEMM: [M x 128] bf16 @ [128 x 40] f32 -> [M x 40] bf16 -

__global__ void k_gemm40(const u16* __restrict__ A, const float* __restrict__ W,
                         u16* __restrict__ C, int M) {
    __shared__ float As[64][132];
    __shared__ float Ws[128][40];
    int t = threadIdx.x;
    int row0 = blockIdx.x * 64;
    #pragma unroll
    for (int i = 0; i < 4; ++i) {
        int fidx = t + i * 256;          // 0..1023
        int r = fidx >> 4;               // 0..63
        int c = (fidx & 15) * 8;         // 0..120
        int gr = row0 + r;
        uint4 v = {0, 0, 0, 0};
        if (gr < M) v = *reinterpret_cast<const uint4*>(A + (size_t)gr * 128 + c);
        const u16* pv = (const u16*)&v;
        #pragma unroll
        for (int q = 0; q < 8; ++q) As[r][c + q] = bf2f(pv[q]);
    }
    #pragma unroll
    for (int i = 0; i < 5; ++i) {
        int fidx = t + i * 256;
        int r = fidx / 10, c = (fidx % 10) << 2;
        float4 v = *reinterpret_cast<const float4*>(W + r * 40 + c);
        *reinterpret_cast<float4*>(&Ws[r][c]) = v;
    }
    __syncthreads();
    int r = t >> 2;
    int cg = t & 3;
    float acc[10];
    #pragma unroll
    for (int j = 0; j < 10; ++j) acc[j] = 0.0f;
    for (int k = 0; k < 128; ++k) {
        float a = As[r][k];
        #pragma unroll
        for (int j = 0; j < 10; ++j)
            acc[j] = fmaf(a, Ws[k][cg * 10 + j], acc[j]);
    }
    int gr = row0 + r;
    if (gr < M) {
        #pragma unroll
        for (int j = 0; j < 10; ++j)
            C[(size_t)gr * 40 + cg * 10 + j] = f2bf(acc[j]);
    }
}

// ---------------- CSR aggregation, bf16 h -> relu'd bf16 out (NF=128) ---

__global__ void k_agg_csr_bf(const u16* __restrict__ h, const float* __restrict__ dinv,
                             const float* __restrict__ bias,
                             const int* __restrict__ rowptr, const int* __restrict__ csr_col,
                             u16* __restrict__ out) {
    int gid = blockIdx.x * 256 + threadIdx.x;
    if (gid >= N_NODES * 32) return;
    int i = gid >> 5;
    int q = (gid & 31) * 4;
    float di = dinv[i];
    float s = di * di;
    ushort4 hv = *reinterpret_cast<const ushort4*>(h + (size_t)i * 128 + q);
    float4 bv = *reinterpret_cast<const float4*>(bias + q);
    float4 acc;
    acc.x = fmaf(bf2f(hv.x), s, bv.x);
    acc.y = fmaf(bf2f(hv.y), s, bv.y);
    acc.z = fmaf(bf2f(hv.z), s, bv.z);
    acc.w = fmaf(bf2f(hv.w), s, bv.w);
    int e = rowptr[i], e1 = rowptr[i + 1];
    for (; e + 1 < e1; e += 2) {
        int c0 = csr_col[e], c1 = csr_col[e + 1];
        float n0 = di * dinv[c0], n1 = di * dinv[c1];
        ushort4 v0 = *reinterpret_cast<const ushort4*>(h + (size_t)c0 * 128 + q);
        ushort4 v1 = *reinterpret_cast<const ushort4*>(h + (size_t)c1 * 128 + q);
        acc.x = fmaf(bf2f(v0.x), n0, acc.x);
        acc.y = fmaf(bf2f(v0.y), n0, acc.y);
        acc.z = fmaf(bf2f(v0.z), n0, acc.z);
        acc.w = fmaf(bf2f(v0.w), n0, acc.w);
        acc.x = fmaf(bf2f(v1.x), n1, acc.x);
        acc.y = fmaf(bf2f(v1.y), n1, acc.y);
        acc.z = fmaf(bf2f(v1.z), n1, acc.z);
        acc.w = fmaf(bf2f(v1.w), n1, acc.w);
    }
    if (e < e1) {
        int c0 = csr_col[e];
        float n0 = di * dinv[c0];
        ushort4 v0 = *reinterpret_cast<const ushort4*>(h + (size_t)c0 * 128 + q);
        acc.x = fmaf(bf2f(v0.x), n0, acc.x);
        acc.y = fmaf(bf2f(v0.y), n0, acc.y);
        acc.z = fmaf(bf2f(v0.z), n0, acc.z);
        acc.w = fmaf(bf2f(v0.w), n0, acc.w);
    }
    ushort4 o;
    o.x = f2bf(fmaxf(acc.x, 0.f));
    o.y = f2bf(fmaxf(acc.y, 0.f));
    o.z = f2bf(fmaxf(acc.z, 0.f));
    o.w = f2bf(fmaxf(acc.w, 0.f));
    *reinterpret_cast<ushort4*>(out + (size_t)i * 128 + q) = o;
}

// ---------------- CSR aggregation, bf16 h (NF=40, layer 3) -> f32 out ---

__global__ void k_agg_csr40_bf(const u16* __restrict__ h, const float* __restrict__ dinv,
                               const float* __restrict__ bias,
                               const int* __restrict__ rowptr, const int* __restrict__ csr_col,
                               float* __restrict__ out) {
    const int TPN = 10;
    int gid = blockIdx.x * 256 + threadIdx.x;
    if (gid >= N_NODES * TPN) return;
    int i = gid / TPN;
    int q = (gid % TPN) * 4;
    float di = dinv[i];
    float s = di * di;
    ushort4 hv = *reinterpret_cast<const ushort4*>(h + (size_t)i * 40 + q);
    float4 bv = *reinterpret_cast<const float4*>(bias + q);
    float4 acc;
    acc.x = fmaf(bf2f(hv.x), s, bv.x);
    acc.y = fmaf(bf2f(hv.y), s, bv.y);
    acc.z = fmaf(bf2f(hv.z), s, bv.z);
    acc.w = fmaf(bf2f(hv.w), s, bv.w);
    int e = rowptr[i], e1 = rowptr[i + 1];
    for (; e + 1 < e1; e += 2) {
        int c0 = csr_col[e], c1 = csr_col[e + 1];
        float n0 = di * dinv[c0], n1 = di * dinv[c1];
        ushort4 v0 = *reinterpret_cast<const ushort4*>(h + (size_t)c0 * 40 + q);
        ushort4 v1 = *reinterpret_cast<const ushort4*>(h + (size_t)c1 * 40 + q);
        acc.x = fmaf(bf2f(v0.x), n0, acc.x);
        acc.y = fmaf(bf2f(v0.y), n0, acc.y);
        acc.z = fmaf(bf2f(v0.z), n0, acc.z);
        acc.w = fmaf(bf2f(v0.w), n0, acc.w);
        acc.x = fmaf(bf2f(v1.x), n1, acc.x);
        acc.y = fmaf(bf2f(v1.y), n1, acc.y);
        acc.z = fmaf(bf2f(v1.z), n1, acc.z);
        acc.w = fmaf(bf2f(v1.w), n1, acc.w);
    }
    if (e < e1) {
        int c0 = csr_col[e];
        float n0 = di * dinv[c0];
        ushort4 v0 = *reinterpret_cast<const ushort4*>(h + (size_t)c0 * 40 + q);
        acc.x = fmaf(bf2f(v0.x), n0, acc.x);
        acc.y = fmaf(bf2f(v0.y), n0, acc.y);
        acc.z = fmaf(bf2f(v0.z), n0, acc.z);
        acc.w = fmaf(bf2f(v0.w), n0, acc.w);
    }
    *reinterpret_cast<float4*>(out + (size_t)i * 40 + q) = acc;
}

// ---------------- log_softmax (in-place, one wave per row) ----------------

__global__ void k_logsoftmax(float* __restrict__ out) {
    int wave = threadIdx.x >> 6, lane = threadIdx.x & 63;
    int rowi = blockIdx.x * 4 + wave;
    if (rowi >= N_NODES) return;
    float v = (lane < NCLS) ? out[(size_t)rowi * NCLS + lane] : -INFINITY;
    float m = v;
    #pragma unroll
    for (int off = 32; off; off >>= 1) m = fmaxf(m, __shfl_xor(m, off));
    float ex = (lane < NCLS) ? expf(v - m) : 0.0f;
    float s = ex;
    #pragma unroll
    for (int off = 32; off; off >>= 1) s += __shfl_xor(s, off);
    float ls = logf(s);
    if (lane < NCLS) out[(size_t)rowi * NCLS + lane] = v - m - ls;
}

// ---------------- launch ----------------

extern "C" void kernel_launch(void* const* d_in, const int* in_sizes, int n_in,
                              void* d_out, int out_size, void* d_ws, size_t ws_size,
                              hipStream_t stream) {
    const float* x  = (const float*)d_in[0];
    const int* ei   = (const int*)d_in[1];
    const float* W1 = (const float*)d_in[2];
    const float* b1 = (const float*)d_in[3];
    const float* W2 = (const float*)d_in[4];
    const float* b2 = (const float*)d_in[5];
    const float* W3 = (const float*)d_in[6];
    const float* b3 = (const float*)d_in[7];
    float* out = (float*)d_out;

    const int* row = ei;             // targets
    const int* col = ei + N_EDGES;   // sources

    char* ws = (char*)d_ws;
    int*   deg      = (int*)ws;   ws += sizeof(int) * (size_t)N_NODES * PAD;
    int*   cursor   = (int*)ws;   ws += sizeof(int) * (size_t)N_NODES * PAD;
    int*   rowptr   = (int*)ws;   ws += sizeof(int) * 50004;
    int*   blocksum = (int*)ws;   ws += sizeof(int) * NBLK;
    int*   blockoff = (int*)ws;   ws += sizeof(int) * 204;
    int*   csr_col  = (int*)ws;   ws += sizeof(int) * N_EDGES;
    float* dinv     = (float*)ws; ws += sizeof(float) * N_NODES;
    u16*   wt1hi    = (u16*)ws;   ws += sizeof(u16) * F_IN * 128;
    u16*   wt2hi    = (u16*)ws;   ws += sizeof(u16) * HID * 128;
    u16*   hbuf     = (u16*)ws;   ws += sizeof(u16) * (size_t)N_NODES * HID;
    u16*   abuf     = (u16*)ws;   ws += sizeof(u16) * (size_t)N_NODES * HID;
    u16*   h3       = (u16*)ws;   ws += sizeof(u16) * (size_t)N_NODES * NCLS;

    const int NB_N = (N_NODES + 255) / 256;
    const int NB_G = (N_NODES + 63) / 64;     // 64-row tiles
    const int NB_BIN = 2048;                  // 256 blocks per bin x 8 bins

    // weight split (fragment-major, once)
    k_wsplit<<<(F_IN * 128 + 255) / 256, 256, 0, stream>>>(W1, wt1hi, F_IN);
    k_wsplit<<<(HID * 128 + 255) / 256, 256, 0, stream>>>(W2, wt2hi, HID);

    // CSR build (once, shared by all 3 layers) — XCD-binned count/scatter
    k_zero_deg<<<NB_N, 256, 0, stream>>>(deg);
    k_count_bin<<<NB_BIN, 256, 0, stream>>>(row, deg);
    k_scan_partial<<<NBLK, 256, 0, stream>>>(deg, blocksum);
    k_scan_block<<<1, 256, 0, stream>>>(blocksum, blockoff);
    k_scan_final<<<NBLK, 256, 0, stream>>>(deg, blockoff, rowptr, cursor, dinv);
    k_scatter_bin<<<NB_BIN, 256, 0, stream>>>(row, col, cursor, csr_col);

    // layer 1: x (f32) @ W1 -> hbuf (bf16)
    k_gemm_lds<F_IN, true><<<NB_G, 256, 0, stream>>>(x, wt1hi, hbuf, N_NODES);
    k_agg_csr_bf<<<(N_NODES * 32 + 255) / 256, 256, 0, stream>>>(
        hbuf, dinv, b1, rowptr, csr_col, abuf);   // -> relu'd bf16

    // layer 2: abuf (bf16) @ W2 -> hbuf (bf16)
    k_gemm_lds<HID, false><<<NB_G, 256, 0, stream>>>(abuf, wt2hi, hbuf, N_NODES);
    k_agg_csr_bf<<<(N_NODES * 32 + 255) / 256, 256, 0, stream>>>(
        hbuf, dinv, b2, rowptr, csr_col, abuf);   // -> relu'd bf16

    // layer 3: abuf (bf16) @ W3 -> h3 (bf16), agg -> f32 out, log_softmax
    k_gemm40<<<NB_G, 256, 0, stream>>>(abuf, W3, h3, N_NODES);
    k_agg_csr40_bf<<<(N_NODES * 10 + 255) / 256, 256, 0, stream>>>(
        h3, dinv, b3, rowptr, csr_col, out);
    k_logsoftmax<<<(N_NODES + 3) / 4, 256, 0, stream>>>(out);
}

// Round 15
// 278.980 us; speedup vs baseline: 1.3638x; 1.0569x over previous
//
#include <hip/hip_runtime.h>
#include <hip/hip_bf16.h>
#include <math.h>

#define N_NODES 50000
#define N_EDGES 800000
#define F_IN 512
#define HID 128
#define NCLS 40
#define NBLK 196   // ceil(N_NODES/256)
#define PAD 16     // ints per 64B line (atomic counter padding)
#define NBIN 8
#define BIN_SZ 6250  // N_NODES / NBIN

typedef unsigned short u16;
typedef __attribute__((ext_vector_type(8))) short short8;
typedef __attribute__((ext_vector_type(4))) float f32x4;

__device__ inline u16 f2bf(float f) {
    unsigned int u = __float_as_uint(f);
    unsigned int r = (u + 0x7FFFu + ((u >> 16) & 1u)) >> 16;
    return (u16)r;
}
__device__ inline float bf2f(u16 b) {
    return __uint_as_float(((unsigned int)b) << 16);
}

// ---------------- CSR build ----------------

__global__ void k_zero_deg(int* __restrict__ deg) {
    int i = blockIdx.x * 256 + threadIdx.x;
    if (i < N_NODES) deg[(size_t)i * PAD] = 0;
}

// XCD-binned degree count
__global__ void k_count_bin(const int* __restrict__ row, int* __restrict__ deg) {
    int bin = blockIdx.x & 7;
    int gblk = blockIdx.x >> 3;
    int nblk = gridDim.x >> 3;
    int lo = bin * BIN_SZ, hi = lo + BIN_SZ;
    for (int e = gblk * 256 + threadIdx.x; e < N_EDGES; e += nblk * 256) {
        int r = row[e];
        if (r >= lo && r < hi) atomicAdd(&deg[(size_t)r * PAD], 1);
    }
}

__device__ inline int wave_incl_scan(int v, int lane) {
    #pragma unroll
    for (int off = 1; off < 64; off <<= 1) {
        int g = __shfl_up(v, off);
        if (lane >= off) v += g;
    }
    return v;
}

__global__ void k_scan_partial(const int* __restrict__ deg, int* __restrict__ blocksum) {
    int t = threadIdx.x;
    int i = blockIdx.x * 256 + t;
    int v = (i < N_NODES) ? deg[(size_t)i * PAD] : 0;
    #pragma unroll
    for (int off = 32; off; off >>= 1) v += __shfl_xor(v, off);
    __shared__ int ws[4];
    if ((t & 63) == 0) ws[t >> 6] = v;
    __syncthreads();
    if (t == 0) blocksum[blockIdx.x] = ws[0] + ws[1] + ws[2] + ws[3];
}

__global__ void k_scan_block(const int* __restrict__ blocksum, int* __restrict__ blockoff) {
    int t = threadIdx.x, lane = t & 63, w = t >> 6;
    int v = (t < NBLK) ? blocksum[t] : 0;
    int incl = wave_incl_scan(v, lane);
    __shared__ int wsum[4];
    if (lane == 63) wsum[w] = incl;
    __syncthreads();
    int woff = 0;
    for (int j = 0; j < w; ++j) woff += wsum[j];
    incl += woff;
    if (t < NBLK) blockoff[t] = incl - v;
    if (t == NBLK - 1) blockoff[NBLK] = incl;
}

__global__ void k_scan_final(const int* __restrict__ deg, const int* __restrict__ blockoff,
                             int* __restrict__ rowptr, int* __restrict__ cursor,
                             float* __restrict__ dinv) {
    int t = threadIdx.x, lane = t & 63, w = t >> 6;
    int i = blockIdx.x * 256 + t;
    int d = (i < N_NODES) ? deg[(size_t)i * PAD] : 0;
    int incl = wave_incl_scan(d, lane);
    __shared__ int wsum[4];
    if (lane == 63) wsum[w] = incl;
    __syncthreads();
    int woff = 0;
    for (int j = 0; j < w; ++j) woff += wsum[j];
    int excl = incl - d + woff + blockoff[blockIdx.x];
    if (i < N_NODES) {
        rowptr[i] = excl;
        cursor[(size_t)i * PAD] = excl;
        dinv[i] = rsqrtf((float)(d + 1));   // +1 self-loop
    }
    if (i == 0) rowptr[N_NODES] = blockoff[NBLK];
}

// XCD-binned scatter
__global__ void k_scatter_bin(const int* __restrict__ row, const int* __restrict__ col,
                              int* __restrict__ cursor, int* __restrict__ csr_col) {
    int bin = blockIdx.x & 7;
    int gblk = blockIdx.x >> 3;
    int nblk = gridDim.x >> 3;
    int lo = bin * BIN_SZ, hi = lo + BIN_SZ;
    for (int e = gblk * 256 + threadIdx.x; e < N_EDGES; e += nblk * 256) {
        int r = row[e];
        if (r >= lo && r < hi) {
            int pos = atomicAdd(&cursor[(size_t)r * PAD], 1);
            csr_col[pos] = col[e];
        }
    }
}

// ---------------- weight split into fragment-major bf16 (hi only) --------
// pos = (((s*8 + j)*16 + ln)*32) + h*8 + q ;  k = s*32 + h*8 + q, n = j*16 + ln

__global__ void k_wsplit(const float* __restrict__ W, u16* __restrict__ Whi, int Kdim) {
    int idx = blockIdx.x * 256 + threadIdx.x;
    if (idx >= Kdim * 128) return;
    int k = idx >> 7, n = idx & 127;
    u16 hb = f2bf(W[idx]);
    int s = k >> 5, hq = (k >> 3) & 3, q = k & 7;
    int j = n >> 4, lnn = n & 15;
    size_t pos = ((((size_t)s * 8 + j) * 16 + lnn) * 32) + hq * 8 + q;
    Whi[pos] = hb;
}

// ---------------- MFMA GEMM, 32-row tile, occupancy-first ----------------
// 1563 blocks (6 blocks/CU -> ~24 waves/CU) x 256 threads (4 waves).
// Wave w computes ALL 32 rows x cols [32w, 32w+32) (acc[2][2]).
// A chunk (32 rows x BK=64) staged via global_load_lds, double-buffered;
// linear DMA dest + inverse-swizzled GLOBAL source + swizzled ds_read
// (rule #21).  B fragment-major from L2 (2 loads/step/thread).

template<int K, bool AF32>
__global__ __launch_bounds__(256) void k_gemm_lds(
    const void* __restrict__ Ap, const u16* __restrict__ Wh,
    u16* __restrict__ C, int M)
{
    constexpr int NC = K / 64;                      // chunks of BK=64
    constexpr int CH_BYTES = AF32 ? 8192 : 4096;    // 32 rows x 64 elems
    __shared__ unsigned char sA[2][CH_BYTES];

    const int t = threadIdx.x;
    const int w = t >> 6, l = t & 63;
    const int ln = l & 15, h = l >> 4;
    const int row0 = blockIdx.x * 32;

    f32x4 acc[2][2];
    #pragma unroll
    for (int i = 0; i < 2; ++i)
        #pragma unroll
        for (int jj = 0; jj < 2; ++jj)
            acc[i][jj] = (f32x4){0.f, 0.f, 0.f, 0.f};

    auto stage = [&](int c, int buf) {
        if constexpr (AF32) {
            const float* X = (const float*)Ap;
            #pragma unroll
            for (int i = 0; i < 2; ++i) {
                int f = i * 256 + t;                 // 0..511 16B-slots
                int r = f >> 4;                      // 0..31
                int sub = f & 15;
                int srow = row0 + r; if (srow > M - 1) srow = M - 1;
                int colf = (sub * 4) ^ ((r & 7) << 3);   // floats
                const float* gp = X + (size_t)srow * K + c * 64 + colf;
                unsigned char* lp = &sA[buf][f * 16];
                __builtin_amdgcn_global_load_lds(
                    (const __attribute__((address_space(1))) void*)gp,
                    (__attribute__((address_space(3))) void*)lp, 16, 0, 0);
            }
        } else {
            const u16* X = (const u16*)Ap;
            int r = t >> 3;                          // 0..31
            int sub = t & 7;
            int srow = row0 + r; if (srow > M - 1) srow = M - 1;
            int cole = (sub * 8) ^ ((r & 7) << 3);   // bf16 elems
            const u16* gp = X + (size_t)srow * K + c * 64 + cole;
            unsigned char* lp = &sA[buf][t * 16];
            __builtin_amdgcn_global_load_lds(
                (const __attribute__((address_space(1))) void*)gp,
                (__attribute__((address_space(3))) void*)lp, 16, 0, 0);
        }
    };

    stage(0, 0);
    __syncthreads();   // drain chunk-0 DMA

    int buf = 0;
    for (int c = 0; c < NC; ++c) {
        // B fragments: wave w needs j = 2w, 2w+1 for both K-steps of chunk
        short8 bh[2][2];
        #pragma unroll
        for (int s = 0; s < 2; ++s) {
            const int sg = c * 2 + s;
            #pragma unroll
            for (int jj = 0; jj < 2; ++jj) {
                size_t off = ((((size_t)sg * 8 + 2 * w + jj) * 16 + ln) * 32) + h * 8;
                bh[s][jj] = *(const short8*)(Wh + off);
            }
        }
        // prefetch next chunk's A (DMA, zero VGPR)
        if (c + 1 < NC) stage(c + 1, buf ^ 1);

        // A fragments from LDS (swizzled reads)
        short8 ah[2][2];   // [step][frag]
        if constexpr (AF32) {
            #pragma unroll
            for (int s = 0; s < 2; ++s)
                #pragma unroll
                for (int i = 0; i < 2; ++i) {
                    int rb = (i * 16 + ln) * 256;
                    int sw = (ln & 7) << 5;
                    int a0 = rb + ((s * 128 + h * 32) ^ sw);
                    float4 p0 = *(const float4*)&sA[buf][a0];
                    float4 p1 = *(const float4*)&sA[buf][a0 + 16];
                    union { short8 s8; u16 u[8]; } cv;
                    cv.u[0] = f2bf(p0.x); cv.u[1] = f2bf(p0.y);
                    cv.u[2] = f2bf(p0.z); cv.u[3] = f2bf(p0.w);
                    cv.u[4] = f2bf(p1.x); cv.u[5] = f2bf(p1.y);
                    cv.u[6] = f2bf(p1.z); cv.u[7] = f2bf(p1.w);
                    ah[s][i] = cv.s8;
                }
        } else {
            #pragma unroll
            for (int s = 0; s < 2; ++s)
                #pragma unroll
                for (int i = 0; i < 2; ++i) {
                    int rb = (i * 16 + ln) * 128;
                    int sw = (ln & 7) << 4;
                    ah[s][i] = *(const short8*)&sA[buf][rb + ((s * 64 + h * 16) ^ sw)];
                }
        }

        #pragma unroll
        for (int s = 0; s < 2; ++s)
            #pragma unroll
            for (int i = 0; i < 2; ++i)
                #pragma unroll
                for (int jj = 0; jj < 2; ++jj)
                    acc[i][jj] = __builtin_amdgcn_mfma_f32_16x16x32_bf16(
                        ah[s][i], bh[s][jj], acc[i][jj], 0, 0, 0);

        __syncthreads();   // drain next-chunk DMA + buffer swap
        buf ^= 1;
    }

    // epilogue: C[row0 + i*16 + h*4 + v][w*32 + jj*16 + ln]
    #pragma unroll
    for (int i = 0; i < 2; ++i)
        #pragma unroll
        for (int v = 0; v < 4; ++v) {
            int gr = row0 + i * 16 + h * 4 + v;
            if (gr < M) {
                #pragma unroll
                for (int jj = 0; jj < 2; ++jj)
                    C[(size_t)gr * 128 + w * 32 + jj * 16 + ln] = f2bf(acc[i][jj][v]);
            }
        }
}

// ---------------- GEMM: [M x 128] bf16 @ [128 x 40] f32 -> [M x 40] bf16 -

__global__ void k_gemm40(const u16* __restrict__ A, const float* __restrict__ W,
                         u16* __restrict__ C, int M) {
    __shared__ float As[64][132];
    __shared__ float Ws[128][40];
    int t = threadIdx.x;
    int row0 = blockIdx.x * 64;
    #pragma unroll
    for (int i = 0; i < 4; ++i) {
        int fidx = t + i * 256;          // 0..1023
        int r = fidx >> 4;               // 0..63
        int c = (fidx & 15) * 8;         // 0..120
        int gr = row0 + r;
        uint4 v = {0, 0, 0, 0};
        if (gr < M) v = *reinterpret_cast<const uint4*>(A + (size_t)gr * 128 + c);
        const u16* pv = (const u16*)&v;
        #pragma unroll
        for (int q = 0; q < 8; ++q) As[r][c + q] = bf2f(pv[q]);
    }
    #pragma unroll
    for (int i = 0; i < 5; ++i) {
        int fidx = t + i * 256;
        int r = fidx / 10, c = (fidx % 10) << 2;
        float4 v = *reinterpret_cast<const float4*>(W + r * 40 + c);
        *reinterpret_cast<float4*>(&Ws[r][c]) = v;
    }
    __syncthreads();
    int r = t >> 2;
    int cg = t & 3;
    float acc[10];
    #pragma unroll
    for (int j = 0; j < 10; ++j) acc[j] = 0.0f;
    for (int k = 0; k < 128; ++k) {
        float a = As[r][k];
        #pragma unroll
        for (int j = 0; j < 10; ++j)
            acc[j] = fmaf(a, Ws[k][cg * 10 + j], acc[j]);
    }
    int gr = row0 + r;
    if (gr < M) {
        #pragma unroll
        for (int j = 0; j < 10; ++j)
            C[(size_t)gr * 40 + cg * 10 + j] = f2bf(acc[j]);
    }
}

// ---------------- CSR aggregation, bf16 h -> relu'd bf16 out (NF=128) ---

__global__ void k_agg_csr_bf(const u16* __restrict__ h, const float* __restrict__ dinv,
                             const float* __restrict__ bias,
                             const int* __restrict__ rowptr, const int* __restrict__ csr_col,
                             u16* __restrict__ out) {
    int gid = blockIdx.x * 256 + threadIdx.x;
    if (gid >= N_NODES * 32) return;
    int i = gid >> 5;
    int q = (gid & 31) * 4;
    float di = dinv[i];
    float s = di * di;
    ushort4 hv = *reinterpret_cast<const ushort4*>(h + (size_t)i * 128 + q);
    float4 bv = *reinterpret_cast<const float4*>(bias + q);
    float4 acc;
    acc.x = fmaf(bf2f(hv.x), s, bv.x);
    acc.y = fmaf(bf2f(hv.y), s, bv.y);
    acc.z = fmaf(bf2f(hv.z), s, bv.z);
    acc.w = fmaf(bf2f(hv.w), s, bv.w);
    int e = rowptr[i], e1 = rowptr[i + 1];
    for (; e + 1 < e1; e += 2) {
        int c0 = csr_col[e], c1 = csr_col[e + 1];
        float n0 = di * dinv[c0], n1 = di * dinv[c1];
        ushort4 v0 = *reinterpret_cast<const ushort4*>(h + (size_t)c0 * 128 + q);
        ushort4 v1 = *reinterpret_cast<const ushort4*>(h + (size_t)c1 * 128 + q);
        acc.x = fmaf(bf2f(v0.x), n0, acc.x);
        acc.y = fmaf(bf2f(v0.y), n0, acc.y);
        acc.z = fmaf(bf2f(v0.z), n0, acc.z);
        acc.w = fmaf(bf2f(v0.w), n0, acc.w);
        acc.x = fmaf(bf2f(v1.x), n1, acc.x);
        acc.y = fmaf(bf2f(v1.y), n1, acc.y);
        acc.z = fmaf(bf2f(v1.z), n1, acc.z);
        acc.w = fmaf(bf2f(v1.w), n1, acc.w);
    }
    if (e < e1) {
        int c0 = csr_col[e];
        float n0 = di * dinv[c0];
        ushort4 v0 = *reinterpret_cast<const ushort4*>(h + (size_t)c0 * 128 + q);
        acc.x = fmaf(bf2f(v0.x), n0, acc.x);
        acc.y = fmaf(bf2f(v0.y), n0, acc.y);
        acc.z = fmaf(bf2f(v0.z), n0, acc.z);
        acc.w = fmaf(bf2f(v0.w), n0, acc.w);
    }
    ushort4 o;
    o.x = f2bf(fmaxf(acc.x, 0.f));
    o.y = f2bf(fmaxf(acc.y, 0.f));
    o.z = f2bf(fmaxf(acc.z, 0.f));
    o.w = f2bf(fmaxf(acc.w, 0.f));
    *reinterpret_cast<ushort4*>(out + (size_t)i * 128 + q) = o;
}

// ---------------- CSR aggregation, bf16 h (NF=40, layer 3) -> f32 out ---

__global__ void k_agg_csr40_bf(const u16* __restrict__ h, const float* __restrict__ dinv,
                               const float* __restrict__ bias,
                               const int* __restrict__ rowptr, const int* __restrict__ csr_col,
                               float* __restrict__ out) {
    const int TPN = 10;
    int gid = blockIdx.x * 256 + threadIdx.x;
    if (gid >= N_NODES * TPN) return;
    int i = gid / TPN;
    int q = (gid % TPN) * 4;
    float di = dinv[i];
    float s = di * di;
    ushort4 hv = *reinterpret_cast<const ushort4*>(h + (size_t)i * 40 + q);
    float4 bv = *reinterpret_cast<const float4*>(bias + q);
    float4 acc;
    acc.x = fmaf(bf2f(hv.x), s, bv.x);
    acc.y = fmaf(bf2f(hv.y), s, bv.y);
    acc.z = fmaf(bf2f(hv.z), s, bv.z);
    acc.w = fmaf(bf2f(hv.w), s, bv.w);
    int e = rowptr[i], e1 = rowptr[i + 1];
    for (; e + 1 < e1; e += 2) {
        int c0 = csr_col[e], c1 = csr_col[e + 1];
        float n0 = di * dinv[c0], n1 = di * dinv[c1];
        ushort4 v0 = *reinterpret_cast<const ushort4*>(h + (size_t)c0 * 40 + q);
        ushort4 v1 = *reinterpret_cast<const ushort4*>(h + (size_t)c1 * 40 + q);
        acc.x = fmaf(bf2f(v0.x), n0, acc.x);
        acc.y = fmaf(bf2f(v0.y), n0, acc.y);
        acc.z = fmaf(bf2f(v0.z), n0, acc.z);
        acc.w = fmaf(bf2f(v0.w), n0, acc.w);
        acc.x = fmaf(bf2f(v1.x), n1, acc.x);
        acc.y = fmaf(bf2f(v1.y), n1, acc.y);
        acc.z = fmaf(bf2f(v1.z), n1, acc.z);
        acc.w = fmaf(bf2f(v1.w), n1, acc.w);
    }
    if (e < e1) {
        int c0 = csr_col[e];
        float n0 = di * dinv[c0];
        ushort4 v0 = *reinterpret_cast<const ushort4*>(h + (size_t)c0 * 40 + q);
        acc.x = fmaf(bf2f(v0.x), n0, acc.x);
        acc.y = fmaf(bf2f(v0.y), n0, acc.y);
        acc.z = fmaf(bf2f(v0.z), n0, acc.z);
        acc.w = fmaf(bf2f(v0.w), n0, acc.w);
    }
    *reinterpret_cast<float4*>(out + (size_t)i * 40 + q) = acc;
}

// ---------------- log_softmax (in-place, one wave per row) ----------------

__global__ void k_logsoftmax(float* __restrict__ out) {
    int wave = threadIdx.x >> 6, lane = threadIdx.x & 63;
    int rowi = blockIdx.x * 4 + wave;
    if (rowi >= N_NODES) return;
    float v = (lane < NCLS) ? out[(size_t)rowi * NCLS + lane] : -INFINITY;
    float m = v;
    #pragma unroll
    for (int off = 32; off; off >>= 1) m = fmaxf(m, __shfl_xor(m, off));
    float ex = (lane < NCLS) ? expf(v - m) : 0.0f;
    float s = ex;
    #pragma unroll
    for (int off = 32; off; off >>= 1) s += __shfl_xor(s, off);
    float ls = logf(s);
    if (lane < NCLS) out[(size_t)rowi * NCLS + lane] = v - m - ls;
}

// ---------------- launch ----------------

extern "C" void kernel_launch(void* const* d_in, const int* in_sizes, int n_in,
                              void* d_out, int out_size, void* d_ws, size_t ws_size,
                              hipStream_t stream) {
    const float* x  = (const float*)d_in[0];
    const int* ei   = (const int*)d_in[1];
    const float* W1 = (const float*)d_in[2];
    const float* b1 = (const float*)d_in[3];
    const float* W2 = (const float*)d_in[4];
    const float* b2 = (const float*)d_in[5];
    const float* W3 = (const float*)d_in[6];
    const float* b3 = (const float*)d_in[7];
    float* out = (float*)d_out;

    const int* row = ei;             // targets
    const int* col = ei + N_EDGES;   // sources

    char* ws = (char*)d_ws;
    int*   deg      = (int*)ws;   ws += sizeof(int) * (size_t)N_NODES * PAD;
    int*   cursor   = (int*)ws;   ws += sizeof(int) * (size_t)N_NODES * PAD;
    int*   rowptr   = (int*)ws;   ws += sizeof(int) * 50004;
    int*   blocksum = (int*)ws;   ws += sizeof(int) * NBLK;
    int*   blockoff = (int*)ws;   ws += sizeof(int) * 204;
    int*   csr_col  = (int*)ws;   ws += sizeof(int) * N_EDGES;
    float* dinv     = (float*)ws; ws += sizeof(float) * N_NODES;
    u16*   wt1hi    = (u16*)ws;   ws += sizeof(u16) * F_IN * 128;
    u16*   wt2hi    = (u16*)ws;   ws += sizeof(u16) * HID * 128;
    u16*   hbuf     = (u16*)ws;   ws += sizeof(u16) * (size_t)N_NODES * HID;
    u16*   abuf     = (u16*)ws;   ws += sizeof(u16) * (size_t)N_NODES * HID;
    u16*   h3       = (u16*)ws;   ws += sizeof(u16) * (size_t)N_NODES * NCLS;

    const int NB_N   = (N_NODES + 255) / 256;
    const int NB_G   = (N_NODES + 63) / 64;    // gemm40
    const int NB_G32 = (N_NODES + 31) / 32;    // 32-row gemm tiles
    const int NB_BIN = 2048;                   // 256 blocks per bin x 8 bins

    // weight split (fragment-major, once)
    k_wsplit<<<(F_IN * 128 + 255) / 256, 256, 0, stream>>>(W1, wt1hi, F_IN);
    k_wsplit<<<(HID * 128 + 255) / 256, 256, 0, stream>>>(W2, wt2hi, HID);

    // CSR build (once, shared by all 3 layers) — XCD-binned count/scatter
    k_zero_deg<<<NB_N, 256, 0, stream>>>(deg);
    k_count_bin<<<NB_BIN, 256, 0, stream>>>(row, deg);
    k_scan_partial<<<NBLK, 256, 0, stream>>>(deg, blocksum);
    k_scan_block<<<1, 256, 0, stream>>>(blocksum, blockoff);
    k_scan_final<<<NBLK, 256, 0, stream>>>(deg, blockoff, rowptr, cursor, dinv);
    k_scatter_bin<<<NB_BIN, 256, 0, stream>>>(row, col, cursor, csr_col);

    // layer 1: x (f32) @ W1 -> hbuf (bf16)
    k_gemm_lds<F_IN, true><<<NB_G32, 256, 0, stream>>>(x, wt1hi, hbuf, N_NODES);
    k_agg_csr_bf<<<(N_NODES * 32 + 255) / 256, 256, 0, stream>>>(
        hbuf, dinv, b1, rowptr, csr_col, abuf);   // -> relu'd bf16

    // layer 2: abuf (bf16) @ W2 -> hbuf (bf16)
    k_gemm_lds<HID, false><<<NB_G32, 256, 0, stream>>>(abuf, wt2hi, hbuf, N_NODES);
    k_agg_csr_bf<<<(N_NODES * 32 + 255) / 256, 256, 0, stream>>>(
        hbuf, dinv, b2, rowptr, csr_col, abuf);   // -> relu'd bf16

    // layer 3: abuf (bf16) @ W3 -> h3 (bf16), agg -> f32 out, log_softmax
    k_gemm40<<<NB_G, 256, 0, stream>>>(abuf, W3, h3, N_NODES);
    k_agg_csr40_bf<<<(N_NODES * 10 + 255) / 256, 256, 0, stream>>>(
        h3, dinv, b3, rowptr, csr_col, out);
    k_logsoftmax<<<(N_NODES + 3) / 4, 256, 0, stream>>>(out);
}

// Round 16
// 261.577 us; speedup vs baseline: 1.4546x; 1.0665x over previous
//
#include <hip/hip_runtime.h>
#include <hip/hip_bf16.h>
#include <math.h>

#define N_NODES 50000
#define N_EDGES 800000
#define F_IN 512
#define HID 128
#define NCLS 40
#define NBLK 196   // ceil(N_NODES/256)
#define PAD 16     // ints per 64B line (atomic counter padding)
#define NBIN 8
#define BIN_SZ 6250  // N_NODES / NBIN

typedef unsigned short u16;
typedef __attribute__((ext_vector_type(8))) short short8;
typedef __attribute__((ext_vector_type(4))) float f32x4;

__device__ inline u16 f2bf(float f) {
    unsigned int u = __float_as_uint(f);
    unsigned int r = (u + 0x7FFFu + ((u >> 16) & 1u)) >> 16;
    return (u16)r;
}
__device__ inline float bf2f(u16 b) {
    return __uint_as_float(((unsigned int)b) << 16);
}

// ---------------- CSR build ----------------

__global__ void k_zero_deg(int* __restrict__ deg) {
    int i = blockIdx.x * 256 + threadIdx.x;
    if (i < N_NODES) deg[(size_t)i * PAD] = 0;
}

// XCD-binned degree count
__global__ void k_count_bin(const int* __restrict__ row, int* __restrict__ deg) {
    int bin = blockIdx.x & 7;
    int gblk = blockIdx.x >> 3;
    int nblk = gridDim.x >> 3;
    int lo = bin * BIN_SZ, hi = lo + BIN_SZ;
    for (int e = gblk * 256 + threadIdx.x; e < N_EDGES; e += nblk * 256) {
        int r = row[e];
        if (r >= lo && r < hi) atomicAdd(&deg[(size_t)r * PAD], 1);
    }
}

__device__ inline int wave_incl_scan(int v, int lane) {
    #pragma unroll
    for (int off = 1; off < 64; off <<= 1) {
        int g = __shfl_up(v, off);
        if (lane >= off) v += g;
    }
    return v;
}

__global__ void k_scan_partial(const int* __restrict__ deg, int* __restrict__ blocksum) {
    int t = threadIdx.x;
    int i = blockIdx.x * 256 + t;
    int v = (i < N_NODES) ? deg[(size_t)i * PAD] : 0;
    #pragma unroll
    for (int off = 32; off; off >>= 1) v += __shfl_xor(v, off);
    __shared__ int ws[4];
    if ((t & 63) == 0) ws[t >> 6] = v;
    __syncthreads();
    if (t == 0) blocksum[blockIdx.x] = ws[0] + ws[1] + ws[2] + ws[3];
}

__global__ void k_scan_block(const int* __restrict__ blocksum, int* __restrict__ blockoff) {
    int t = threadIdx.x, lane = t & 63, w = t >> 6;
    int v = (t < NBLK) ? blocksum[t] : 0;
    int incl = wave_incl_scan(v, lane);
    __shared__ int wsum[4];
    if (lane == 63) wsum[w] = incl;
    __syncthreads();
    int woff = 0;
    for (int j = 0; j < w; ++j) woff += wsum[j];
    incl += woff;
    if (t < NBLK) blockoff[t] = incl - v;
    if (t == NBLK - 1) blockoff[NBLK] = incl;
}

__global__ void k_scan_final(const int* __restrict__ deg, const int* __restrict__ blockoff,
                             int* __restrict__ rowptr, int* __restrict__ cursor,
                             float* __restrict__ dinv) {
    int t = threadIdx.x, lane = t & 63, w = t >> 6;
    int i = blockIdx.x * 256 + t;
    int d = (i < N_NODES) ? deg[(size_t)i * PAD] : 0;
    int incl = wave_incl_scan(d, lane);
    __shared__ int wsum[4];
    if (lane == 63) wsum[w] = incl;
    __syncthreads();
    int woff = 0;
    for (int j = 0; j < w; ++j) woff += wsum[j];
    int excl = incl - d + woff + blockoff[blockIdx.x];
    if (i < N_NODES) {
        rowptr[i] = excl;
        cursor[(size_t)i * PAD] = excl;
        dinv[i] = rsqrtf((float)(d + 1));   // +1 self-loop
    }
    if (i == 0) rowptr[N_NODES] = blockoff[NBLK];
}

// XCD-binned scatter; also materializes csr_nrm (removes the random
// dinv[c] gather from all three agg kernels -> half the random requests)
__global__ void k_scatter_bin(const int* __restrict__ row, const int* __restrict__ col,
                              const float* __restrict__ dinv, int* __restrict__ cursor,
                              int* __restrict__ csr_col, float* __restrict__ csr_nrm) {
    int bin = blockIdx.x & 7;
    int gblk = blockIdx.x >> 3;
    int nblk = gridDim.x >> 3;
    int lo = bin * BIN_SZ, hi = lo + BIN_SZ;
    for (int e = gblk * 256 + threadIdx.x; e < N_EDGES; e += nblk * 256) {
        int r = row[e];
        if (r >= lo && r < hi) {
            int c = col[e];
            int pos = atomicAdd(&cursor[(size_t)r * PAD], 1);
            csr_col[pos] = c;
            csr_nrm[pos] = dinv[r] * dinv[c];
        }
    }
}

// ---------------- weight split into fragment-major bf16 (hi only) --------
// pos = (((s*8 + j)*16 + ln)*32) + h*8 + q ;  k = s*32 + h*8 + q, n = j*16 + ln

__global__ void k_wsplit(const float* __restrict__ W, u16* __restrict__ Whi, int Kdim) {
    int idx = blockIdx.x * 256 + threadIdx.x;
    if (idx >= Kdim * 128) return;
    int k = idx >> 7, n = idx & 127;
    u16 hb = f2bf(W[idx]);
    int s = k >> 5, hq = (k >> 3) & 3, q = k & 7;
    int j = n >> 4, lnn = n & 15;
    size_t pos = ((((size_t)s * 8 + j) * 16 + lnn) * 32) + hq * 8 + q;
    Whi[pos] = hb;
}

// ---------------- MFMA GEMM, 32-row tile (round-15 state, frozen) --------

template<int K, bool AF32>
__global__ __launch_bounds__(256) void k_gemm_lds(
    const void* __restrict__ Ap, const u16* __restrict__ Wh,
    u16* __restrict__ C, int M)
{
    constexpr int NC = K / 64;
    constexpr int CH_BYTES = AF32 ? 8192 : 4096;
    __shared__ unsigned char sA[2][CH_BYTES];

    const int t = threadIdx.x;
    const int w = t >> 6, l = t & 63;
    const int ln = l & 15, h = l >> 4;
    const int row0 = blockIdx.x * 32;

    f32x4 acc[2][2];
    #pragma unroll
    for (int i = 0; i < 2; ++i)
        #pragma unroll
        for (int jj = 0; jj < 2; ++jj)
            acc[i][jj] = (f32x4){0.f, 0.f, 0.f, 0.f};

    auto stage = [&](int c, int buf) {
        if constexpr (AF32) {
            const float* X = (const float*)Ap;
            #pragma unroll
            for (int i = 0; i < 2; ++i) {
                int f = i * 256 + t;
                int r = f >> 4;
                int sub = f & 15;
                int srow = row0 + r; if (srow > M - 1) srow = M - 1;
                int colf = (sub * 4) ^ ((r & 7) << 3);
                const float* gp = X + (size_t)srow * K + c * 64 + colf;
                unsigned char* lp = &sA[buf][f * 16];
                __builtin_amdgcn_global_load_lds(
                    (const __attribute__((address_space(1))) void*)gp,
                    (__attribute__((address_space(3))) void*)lp, 16, 0, 0);
            }
        } else {
            const u16* X = (const u16*)Ap;
            int r = t >> 3;
            int sub = t & 7;
            int srow = row0 + r; if (srow > M - 1) srow = M - 1;
            int cole = (sub * 8) ^ ((r & 7) << 3);
            const u16* gp = X + (size_t)srow * K + c * 64 + cole;
            unsigned char* lp = &sA[buf][t * 16];
            __builtin_amdgcn_global_load_lds(
                (const __attribute__((address_space(1))) void*)gp,
                (__attribute__((address_space(3))) void*)lp, 16, 0, 0);
        }
    };

    stage(0, 0);
    __syncthreads();

    int buf = 0;
    for (int c = 0; c < NC; ++c) {
        short8 bh[2][2];
        #pragma unroll
        for (int s = 0; s < 2; ++s) {
            const int sg = c * 2 + s;
            #pragma unroll
            for (int jj = 0; jj < 2; ++jj) {
                size_t off = ((((size_t)sg * 8 + 2 * w + jj) * 16 + ln) * 32) + h * 8;
                bh[s][jj] = *(const short8*)(Wh + off);
            }
        }
        if (c + 1 < NC) stage(c + 1, buf ^ 1);

        short8 ah[2][2];
        if constexpr (AF32) {
            #pragma unroll
            for (int s = 0; s < 2; ++s)
                #pragma unroll
                for (int i = 0; i < 2; ++i) {
                    int rb = (i * 16 + ln) * 256;
                    int sw = (ln & 7) << 5;
                    int a0 = rb + ((s * 128 + h * 32) ^ sw);
                    float4 p0 = *(const float4*)&sA[buf][a0];
                    float4 p1 = *(const float4*)&sA[buf][a0 + 16];
                    union { short8 s8; u16 u[8]; } cv;
                    cv.u[0] = f2bf(p0.x); cv.u[1] = f2bf(p0.y);
                    cv.u[2] = f2bf(p0.z); cv.u[3] = f2bf(p0.w);
                    cv.u[4] = f2bf(p1.x); cv.u[5] = f2bf(p1.y);
                    cv.u[6] = f2bf(p1.z); cv.u[7] = f2bf(p1.w);
                    ah[s][i] = cv.s8;
                }
        } else {
            #pragma unroll
            for (int s = 0; s < 2; ++s)
                #pragma unroll
                for (int i = 0; i < 2; ++i) {
                    int rb = (i * 16 + ln) * 128;
                    int sw = (ln & 7) << 4;
                    ah[s][i] = *(const short8*)&sA[buf][rb + ((s * 64 + h * 16) ^ sw)];
                }
        }

        #pragma unroll
        for (int s = 0; s < 2; ++s)
            #pragma unroll
            for (int i = 0; i < 2; ++i)
                #pragma unroll
                for (int jj = 0; jj < 2; ++jj)
                    acc[i][jj] = __builtin_amdgcn_mfma_f32_16x16x32_bf16(
                        ah[s][i], bh[s][jj], acc[i][jj], 0, 0, 0);

        __syncthreads();
        buf ^= 1;
    }

    #pragma unroll
    for (int i = 0; i < 2; ++i)
        #pragma unroll
        for (int v = 0; v < 4; ++v) {
            int gr = row0 + i * 16 + h * 4 + v;
            if (gr < M) {
                #pragma unroll
                for (int jj = 0; jj < 2; ++jj)
                    C[(size_t)gr * 128 + w * 32 + jj * 16 + ln] = f2bf(acc[i][jj][v]);
            }
        }
}

// ---------------- GEMM: [M x 128] bf16 @ [128 x 40] f32 -> [M x 40] bf16 -

__global__ void k_gemm40(const u16* __restrict__ A, const float* __restrict__ W,
                         u16* __restrict__ C, int M) {
    __shared__ float As[64][132];
    __shared__ float Ws[128][40];
    int t = threadIdx.x;
    int row0 = blockIdx.x * 64;
    #pragma unroll
    for (int i = 0; i < 4; ++i) {
        int fidx = t + i * 256;
        int r = fidx >> 4;
        int c = (fidx & 15) * 8;
        int gr = row0 + r;
        uint4 v = {0, 0, 0, 0};
        if (gr < M) v = *reinterpret_cast<const uint4*>(A + (size_t)gr * 128 + c);
        const u16* pv = (const u16*)&v;
        #pragma unroll
        for (int q = 0; q < 8; ++q) As[r][c + q] = bf2f(pv[q]);
    }
    #pragma unroll
    for (int i = 0; i < 5; ++i) {
        int fidx = t + i * 256;
        int r = fidx / 10, c = (fidx % 10) << 2;
        float4 v = *reinterpret_cast<const float4*>(W + r * 40 + c);
        *reinterpret_cast<float4*>(&Ws[r][c]) = v;
    }
    __syncthreads();
    int r = t >> 2;
    int cg = t & 3;
    float acc[10];
    #pragma unroll
    for (int j = 0; j < 10; ++j) acc[j] = 0.0f;
    for (int k = 0; k < 128; ++k) {
        float a = As[r][k];
        #pragma unroll
        for (int j = 0; j < 10; ++j)
            acc[j] = fmaf(a, Ws[k][cg * 10 + j], acc[j]);
    }
    int gr = row0 + r;
    if (gr < M) {
        #pragma unroll
        for (int j = 0; j < 10; ++j)
            C[(size_t)gr * 40 + cg * 10 + j] = f2bf(acc[j]);
    }
}

// ---------------- CSR aggregation, bf16 h -> relu'd bf16 out (NF=128) ---
// 4-wide unrolled gather: 4 independent h-row loads in flight per thread;
// norm from sequential csr_nrm (no random dinv gather).

__global__ void k_agg_csr_bf(const u16* __restrict__ h, const float* __restrict__ dinv,
                             const float* __restrict__ bias,
                             const int* __restrict__ rowptr, const int* __restrict__ csr_col,
                             const float* __restrict__ csr_nrm, u16* __restrict__ out) {
    int gid = blockIdx.x * 256 + threadIdx.x;
    if (gid >= N_NODES * 32) return;
    int i = gid >> 5;
    int q = (gid & 31) * 4;
    const u16* hq = h + q;
    float di = dinv[i];
    float s = di * di;
    ushort4 hv = *reinterpret_cast<const ushort4*>(hq + (size_t)i * 128);
    float4 bv = *reinterpret_cast<const float4*>(bias + q);
    float4 acc;
    acc.x = fmaf(bf2f(hv.x), s, bv.x);
    acc.y = fmaf(bf2f(hv.y), s, bv.y);
    acc.z = fmaf(bf2f(hv.z), s, bv.z);
    acc.w = fmaf(bf2f(hv.w), s, bv.w);
    int e = rowptr[i], e1 = rowptr[i + 1];
    for (; e + 4 <= e1; e += 4) {
        int c0 = csr_col[e], c1 = csr_col[e + 1], c2 = csr_col[e + 2], c3 = csr_col[e + 3];
        float n0 = csr_nrm[e], n1 = csr_nrm[e + 1], n2 = csr_nrm[e + 2], n3 = csr_nrm[e + 3];
        ushort4 v0 = *reinterpret_cast<const ushort4*>(hq + (size_t)c0 * 128);
        ushort4 v1 = *reinterpret_cast<const ushort4*>(hq + (size_t)c1 * 128);
        ushort4 v2 = *reinterpret_cast<const ushort4*>(hq + (size_t)c2 * 128);
        ushort4 v3 = *reinterpret_cast<const ushort4*>(hq + (size_t)c3 * 128);
        acc.x = fmaf(bf2f(v0.x), n0, acc.x);
        acc.y = fmaf(bf2f(v0.y), n0, acc.y);
        acc.z = fmaf(bf2f(v0.z), n0, acc.z);
        acc.w = fmaf(bf2f(v0.w), n0, acc.w);
        acc.x = fmaf(bf2f(v1.x), n1, acc.x);
        acc.y = fmaf(bf2f(v1.y), n1, acc.y);
        acc.z = fmaf(bf2f(v1.z), n1, acc.z);
        acc.w = fmaf(bf2f(v1.w), n1, acc.w);
        acc.x = fmaf(bf2f(v2.x), n2, acc.x);
        acc.y = fmaf(bf2f(v2.y), n2, acc.y);
        acc.z = fmaf(bf2f(v2.z), n2, acc.z);
        acc.w = fmaf(bf2f(v2.w), n2, acc.w);
        acc.x = fmaf(bf2f(v3.x), n3, acc.x);
        acc.y = fmaf(bf2f(v3.y), n3, acc.y);
        acc.z = fmaf(bf2f(v3.z), n3, acc.z);
        acc.w = fmaf(bf2f(v3.w), n3, acc.w);
    }
    for (; e < e1; ++e) {
        int c0 = csr_col[e];
        float n0 = csr_nrm[e];
        ushort4 v0 = *reinterpret_cast<const ushort4*>(hq + (size_t)c0 * 128);
        acc.x = fmaf(bf2f(v0.x), n0, acc.x);
        acc.y = fmaf(bf2f(v0.y), n0, acc.y);
        acc.z = fmaf(bf2f(v0.z), n0, acc.z);
        acc.w = fmaf(bf2f(v0.w), n0, acc.w);
    }
    ushort4 o;
    o.x = f2bf(fmaxf(acc.x, 0.f));
    o.y = f2bf(fmaxf(acc.y, 0.f));
    o.z = f2bf(fmaxf(acc.z, 0.f));
    o.w = f2bf(fmaxf(acc.w, 0.f));
    *reinterpret_cast<ushort4*>(out + (size_t)i * 128 + q) = o;
}

// ---------------- CSR aggregation, bf16 h (NF=40, layer 3) -> f32 out ---

__global__ void k_agg_csr40_bf(const u16* __restrict__ h, const float* __restrict__ dinv,
                               const float* __restrict__ bias,
                               const int* __restrict__ rowptr, const int* __restrict__ csr_col,
                               const float* __restrict__ csr_nrm, float* __restrict__ out) {
    const int TPN = 10;
    int gid = blockIdx.x * 256 + threadIdx.x;
    if (gid >= N_NODES * TPN) return;
    int i = gid / TPN;
    int q = (gid % TPN) * 4;
    const u16* hq = h + q;
    float di = dinv[i];
    float s = di * di;
    ushort4 hv = *reinterpret_cast<const ushort4*>(hq + (size_t)i * 40);
    float4 bv = *reinterpret_cast<const float4*>(bias + q);
    float4 acc;
    acc.x = fmaf(bf2f(hv.x), s, bv.x);
    acc.y = fmaf(bf2f(hv.y), s, bv.y);
    acc.z = fmaf(bf2f(hv.z), s, bv.z);
    acc.w = fmaf(bf2f(hv.w), s, bv.w);
    int e = rowptr[i], e1 = rowptr[i + 1];
    for (; e + 4 <= e1; e += 4) {
        int c0 = csr_col[e], c1 = csr_col[e + 1], c2 = csr_col[e + 2], c3 = csr_col[e + 3];
        float n0 = csr_nrm[e], n1 = csr_nrm[e + 1], n2 = csr_nrm[e + 2], n3 = csr_nrm[e + 3];
        ushort4 v0 = *reinterpret_cast<const ushort4*>(hq + (size_t)c0 * 40);
        ushort4 v1 = *reinterpret_cast<const ushort4*>(hq + (size_t)c1 * 40);
        ushort4 v2 = *reinterpret_cast<const ushort4*>(hq + (size_t)c2 * 40);
        ushort4 v3 = *reinterpret_cast<const ushort4*>(hq + (size_t)c3 * 40);
        acc.x = fmaf(bf2f(v0.x), n0, acc.x);
        acc.y = fmaf(bf2f(v0.y), n0, acc.y);
        acc.z = fmaf(bf2f(v0.z), n0, acc.z);
        acc.w = fmaf(bf2f(v0.w), n0, acc.w);
        acc.x = fmaf(bf2f(v1.x), n1, acc.x);
        acc.y = fmaf(bf2f(v1.y), n1, acc.y);
        acc.z = fmaf(bf2f(v1.z), n1, acc.z);
        acc.w = fmaf(bf2f(v1.w), n1, acc.w);
        acc.x = fmaf(bf2f(v2.x), n2, acc.x);
        acc.y = fmaf(bf2f(v2.y), n2, acc.y);
        acc.z = fmaf(bf2f(v2.z), n2, acc.z);
        acc.w = fmaf(bf2f(v2.w), n2, acc.w);
        acc.x = fmaf(bf2f(v3.x), n3, acc.x);
        acc.y = fmaf(bf2f(v3.y), n3, acc.y);
        acc.z = fmaf(bf2f(v3.z), n3, acc.z);
        acc.w = fmaf(bf2f(v3.w), n3, acc.w);
    }
    for (; e < e1; ++e) {
        int c0 = csr_col[e];
        float n0 = csr_nrm[e];
        ushort4 v0 = *reinterpret_cast<const ushort4*>(hq + (size_t)c0 * 40);
        acc.x = fmaf(bf2f(v0.x), n0, acc.x);
        acc.y = fmaf(bf2f(v0.y), n0, acc.y);
        acc.z = fmaf(bf2f(v0.z), n0, acc.z);
        acc.w = fmaf(bf2f(v0.w), n0, acc.w);
    }
    *reinterpret_cast<float4*>(out + (size_t)i * 40 + q) = acc;
}

// ---------------- log_softmax (in-place, one wave per row) ----------------

__global__ void k_logsoftmax(float* __restrict__ out) {
    int wave = threadIdx.x >> 6, lane = threadIdx.x & 63;
    int rowi = blockIdx.x * 4 + wave;
    if (rowi >= N_NODES) return;
    float v = (lane < NCLS) ? out[(size_t)rowi * NCLS + lane] : -INFINITY;
    float m = v;
    #pragma unroll
    for (int off = 32; off; off >>= 1) m = fmaxf(m, __shfl_xor(m, off));
    float ex = (lane < NCLS) ? expf(v - m) : 0.0f;
    float s = ex;
    #pragma unroll
    for (int off = 32; off; off >>= 1) s += __shfl_xor(s, off);
    float ls = logf(s);
    if (lane < NCLS) out[(size_t)rowi * NCLS + lane] = v - m - ls;
}

// ---------------- launch ----------------

extern "C" void kernel_launch(void* const* d_in, const int* in_sizes, int n_in,
                              void* d_out, int out_size, void* d_ws, size_t ws_size,
                              hipStream_t stream) {
    const float* x  = (const float*)d_in[0];
    const int* ei   = (const int*)d_in[1];
    const float* W1 = (const float*)d_in[2];
    const float* b1 = (const float*)d_in[3];
    const float* W2 = (const float*)d_in[4];
    const float* b2 = (const float*)d_in[5];
    const float* W3 = (const float*)d_in[6];
    const float* b3 = (const float*)d_in[7];
    float* out = (float*)d_out;

    const int* row = ei;             // targets
    const int* col = ei + N_EDGES;   // sources

    char* ws = (char*)d_ws;
    int*   deg      = (int*)ws;   ws += sizeof(int) * (size_t)N_NODES * PAD;
    int*   cursor   = (int*)ws;   ws += sizeof(int) * (size_t)N_NODES * PAD;
    int*   rowptr   = (int*)ws;   ws += sizeof(int) * 50004;
    int*   blocksum = (int*)ws;   ws += sizeof(int) * NBLK;
    int*   blockoff = (int*)ws;   ws += sizeof(int) * 204;
    int*   csr_col  = (int*)ws;   ws += sizeof(int) * N_EDGES;
    float* csr_nrm  = (float*)ws; ws += sizeof(float) * N_EDGES;
    float* dinv     = (float*)ws; ws += sizeof(float) * N_NODES;
    u16*   wt1hi    = (u16*)ws;   ws += sizeof(u16) * F_IN * 128;
    u16*   wt2hi    = (u16*)ws;   ws += sizeof(u16) * HID * 128;
    u16*   hbuf     = (u16*)ws;   ws += sizeof(u16) * (size_t)N_NODES * HID;
    u16*   abuf     = (u16*)ws;   ws += sizeof(u16) * (size_t)N_NODES * HID;
    u16*   h3       = (u16*)ws;   ws += sizeof(u16) * (size_t)N_NODES * NCLS;

    const int NB_N   = (N_NODES + 255) / 256;
    const int NB_G   = (N_NODES + 63) / 64;    // gemm40
    const int NB_G32 = (N_NODES + 31) / 32;    // 32-row gemm tiles
    const int NB_BIN = 2048;                   // 256 blocks per bin x 8 bins

    // weight split (fragment-major, once)
    k_wsplit<<<(F_IN * 128 + 255) / 256, 256, 0, stream>>>(W1, wt1hi, F_IN);
    k_wsplit<<<(HID * 128 + 255) / 256, 256, 0, stream>>>(W2, wt2hi, HID);

    // CSR build (once, shared by all 3 layers) — XCD-binned count/scatter
    k_zero_deg<<<NB_N, 256, 0, stream>>>(deg);
    k_count_bin<<<NB_BIN, 256, 0, stream>>>(row, deg);
    k_scan_partial<<<NBLK, 256, 0, stream>>>(deg, blocksum);
    k_scan_block<<<1, 256, 0, stream>>>(blocksum, blockoff);
    k_scan_final<<<NBLK, 256, 0, stream>>>(deg, blockoff, rowptr, cursor, dinv);
    k_scatter_bin<<<NB_BIN, 256, 0, stream>>>(row, col, dinv, cursor, csr_col, csr_nrm);

    // layer 1: x (f32) @ W1 -> hbuf (bf16)
    k_gemm_lds<F_IN, true><<<NB_G32, 256, 0, stream>>>(x, wt1hi, hbuf, N_NODES);
    k_agg_csr_bf<<<(N_NODES * 32 + 255) / 256, 256, 0, stream>>>(
        hbuf, dinv, b1, rowptr, csr_col, csr_nrm, abuf);   // -> relu'd bf16

    // layer 2: abuf (bf16) @ W2 -> hbuf (bf16)
    k_gemm_lds<HID, false><<<NB_G32, 256, 0, stream>>>(abuf, wt2hi, hbuf, N_NODES);
    k_agg_csr_bf<<<(N_NODES * 32 + 255) / 256, 256, 0, stream>>>(
        hbuf, dinv, b2, rowptr, csr_col, csr_nrm, abuf);   // -> relu'd bf16

    // layer 3: abuf (bf16) @ W3 -> h3 (bf16), agg -> f32 out, log_softmax
    k_gemm40<<<NB_G, 256, 0, stream>>>(abuf, W3, h3, N_NODES);
    k_agg_csr40_bf<<<(N_NODES * 10 + 255) / 256, 256, 0, stream>>>(
        h3, dinv, b3, rowptr, csr_col, csr_nrm, out);
    k_logsoftmax<<<(N_NODES + 3) / 4, 256, 0, stream>>>(out);
}

// Round 17
// 258.691 us; speedup vs baseline: 1.4708x; 1.0112x over previous
//
#include <hip/hip_runtime.h>
#include <hip/hip_bf16.h>
#include <math.h>

#define N_NODES 50000
#define N_EDGES 800000
#define F_IN 512
#define HID 128
#define NCLS 40
#define NBLK 196   // ceil(N_NODES/256)
#define PAD 16     // ints per 64B line (atomic counter padding)
#define NBIN 8
#define BIN_SZ 6250  // N_NODES / NBIN

typedef unsigned short u16;
typedef __attribute__((ext_vector_type(8))) short short8;
typedef __attribute__((ext_vector_type(4))) float f32x4;

__device__ inline u16 f2bf(float f) {
    unsigned int u = __float_as_uint(f);
    unsigned int r = (u + 0x7FFFu + ((u >> 16) & 1u)) >> 16;
    return (u16)r;
}
__device__ inline float bf2f(u16 b) {
    return __uint_as_float(((unsigned int)b) << 16);
}

// ---------------- CSR build ----------------

__global__ void k_zero_deg(int* __restrict__ deg) {
    int i = blockIdx.x * 256 + threadIdx.x;
    if (i < N_NODES) deg[(size_t)i * PAD] = 0;
}

__global__ void k_count_bin(const int* __restrict__ row, int* __restrict__ deg) {
    int bin = blockIdx.x & 7;
    int gblk = blockIdx.x >> 3;
    int nblk = gridDim.x >> 3;
    int lo = bin * BIN_SZ, hi = lo + BIN_SZ;
    for (int e = gblk * 256 + threadIdx.x; e < N_EDGES; e += nblk * 256) {
        int r = row[e];
        if (r >= lo && r < hi) atomicAdd(&deg[(size_t)r * PAD], 1);
    }
}

__device__ inline int wave_incl_scan(int v, int lane) {
    #pragma unroll
    for (int off = 1; off < 64; off <<= 1) {
        int g = __shfl_up(v, off);
        if (lane >= off) v += g;
    }
    return v;
}

__global__ void k_scan_partial(const int* __restrict__ deg, int* __restrict__ blocksum) {
    int t = threadIdx.x;
    int i = blockIdx.x * 256 + t;
    int v = (i < N_NODES) ? deg[(size_t)i * PAD] : 0;
    #pragma unroll
    for (int off = 32; off; off >>= 1) v += __shfl_xor(v, off);
    __shared__ int ws[4];
    if ((t & 63) == 0) ws[t >> 6] = v;
    __syncthreads();
    if (t == 0) blocksum[blockIdx.x] = ws[0] + ws[1] + ws[2] + ws[3];
}

__global__ void k_scan_block(const int* __restrict__ blocksum, int* __restrict__ blockoff) {
    int t = threadIdx.x, lane = t & 63, w = t >> 6;
    int v = (t < NBLK) ? blocksum[t] : 0;
    int incl = wave_incl_scan(v, lane);
    __shared__ int wsum[4];
    if (lane == 63) wsum[w] = incl;
    __syncthreads();
    int woff = 0;
    for (int j = 0; j < w; ++j) woff += wsum[j];
    incl += woff;
    if (t < NBLK) blockoff[t] = incl - v;
    if (t == NBLK - 1) blockoff[NBLK] = incl;
}

__global__ void k_scan_final(const int* __restrict__ deg, const int* __restrict__ blockoff,
                             int* __restrict__ rowptr, int* __restrict__ cursor,
                             float* __restrict__ dinv) {
    int t = threadIdx.x, lane = t & 63, w = t >> 6;
    int i = blockIdx.x * 256 + t;
    int d = (i < N_NODES) ? deg[(size_t)i * PAD] : 0;
    int incl = wave_incl_scan(d, lane);
    __shared__ int wsum[4];
    if (lane == 63) wsum[w] = incl;
    __syncthreads();
    int woff = 0;
    for (int j = 0; j < w; ++j) woff += wsum[j];
    int excl = incl - d + woff + blockoff[blockIdx.x];
    if (i < N_NODES) {
        rowptr[i] = excl;
        cursor[(size_t)i * PAD] = excl;
        dinv[i] = rsqrtf((float)(d + 1));   // +1 self-loop
    }
    if (i == 0) rowptr[N_NODES] = blockoff[NBLK];
}

__global__ void k_scatter_bin(const int* __restrict__ row, const int* __restrict__ col,
                              const float* __restrict__ dinv, int* __restrict__ cursor,
                              int* __restrict__ csr_col, float* __restrict__ csr_nrm) {
    int bin = blockIdx.x & 7;
    int gblk = blockIdx.x >> 3;
    int nblk = gridDim.x >> 3;
    int lo = bin * BIN_SZ, hi = lo + BIN_SZ;
    for (int e = gblk * 256 + threadIdx.x; e < N_EDGES; e += nblk * 256) {
        int r = row[e];
        if (r >= lo && r < hi) {
            int c = col[e];
            int pos = atomicAdd(&cursor[(size_t)r * PAD], 1);
            csr_col[pos] = c;
            csr_nrm[pos] = dinv[r] * dinv[c];
        }
    }
}

// ---------------- weight split into fragment-major bf16 (hi only) --------

__global__ void k_wsplit(const float* __restrict__ W, u16* __restrict__ Whi, int Kdim) {
    int idx = blockIdx.x * 256 + threadIdx.x;
    if (idx >= Kdim * 128) return;
    int k = idx >> 7, n = idx & 127;
    u16 hb = f2bf(W[idx]);
    int s = k >> 5, hq = (k >> 3) & 3, q = k & 7;
    int j = n >> 4, lnn = n & 15;
    size_t pos = ((((size_t)s * 8 + j) * 16 + lnn) * 32) + hq * 8 + q;
    Whi[pos] = hb;
}

// ---------------- MFMA GEMM body (32-row tile, DMA A-staging) ------------
// NT stores on C: bypass the L2 write path (write-rate theory test).

template<int K, bool AF32>
__device__ __forceinline__ void gemm_body(const void* __restrict__ Ap,
                                          const u16* __restrict__ Wh,
                                          u16* __restrict__ C, int M) {
    constexpr int NC = K / 64;
    constexpr int CH_BYTES = AF32 ? 8192 : 4096;
    __shared__ unsigned char sA[2][CH_BYTES];

    const int t = threadIdx.x;
    const int w = t >> 6, l = t & 63;
    const int ln = l & 15, h = l >> 4;
    const int row0 = blockIdx.x * 32;

    f32x4 acc[2][2];
    #pragma unroll
    for (int i = 0; i < 2; ++i)
        #pragma unroll
        for (int jj = 0; jj < 2; ++jj)
            acc[i][jj] = (f32x4){0.f, 0.f, 0.f, 0.f};

    auto stage = [&](int c, int buf) {
        if constexpr (AF32) {
            const float* X = (const float*)Ap;
            #pragma unroll
            for (int i = 0; i < 2; ++i) {
                int f = i * 256 + t;
                int r = f >> 4;
                int sub = f & 15;
                int srow = row0 + r; if (srow > M - 1) srow = M - 1;
                int colf = (sub * 4) ^ ((r & 7) << 3);
                const float* gp = X + (size_t)srow * K + c * 64 + colf;
                unsigned char* lp = &sA[buf][f * 16];
                __builtin_amdgcn_global_load_lds(
                    (const __attribute__((address_space(1))) void*)gp,
                    (__attribute__((address_space(3))) void*)lp, 16, 0, 0);
            }
        } else {
            const u16* X = (const u16*)Ap;
            int r = t >> 3;
            int sub = t & 7;
            int srow = row0 + r; if (srow > M - 1) srow = M - 1;
            int cole = (sub * 8) ^ ((r & 7) << 3);
            const u16* gp = X + (size_t)srow * K + c * 64 + cole;
            unsigned char* lp = &sA[buf][t * 16];
            __builtin_amdgcn_global_load_lds(
                (const __attribute__((address_space(1))) void*)gp,
                (__attribute__((address_space(3))) void*)lp, 16, 0, 0);
        }
    };

    stage(0, 0);
    __syncthreads();

    int buf = 0;
    for (int c = 0; c < NC; ++c) {
        short8 bh[2][2];
        #pragma unroll
        for (int s = 0; s < 2; ++s) {
            const int sg = c * 2 + s;
            #pragma unroll
            for (int jj = 0; jj < 2; ++jj) {
                size_t off = ((((size_t)sg * 8 + 2 * w + jj) * 16 + ln) * 32) + h * 8;
                bh[s][jj] = *(const short8*)(Wh + off);
            }
        }
        if (c + 1 < NC) stage(c + 1, buf ^ 1);

        short8 ah[2][2];
        if constexpr (AF32) {
            #pragma unroll
            for (int s = 0; s < 2; ++s)
                #pragma unroll
                for (int i = 0; i < 2; ++i) {
                    int rb = (i * 16 + ln) * 256;
                    int sw = (ln & 7) << 5;
                    int a0 = rb + ((s * 128 + h * 32) ^ sw);
                    float4 p0 = *(const float4*)&sA[buf][a0];
                    float4 p1 = *(const float4*)&sA[buf][a0 + 16];
                    union { short8 s8; u16 u[8]; } cv;
                    cv.u[0] = f2bf(p0.x); cv.u[1] = f2bf(p0.y);
                    cv.u[2] = f2bf(p0.z); cv.u[3] = f2bf(p0.w);
                    cv.u[4] = f2bf(p1.x); cv.u[5] = f2bf(p1.y);
                    cv.u[6] = f2bf(p1.z); cv.u[7] = f2bf(p1.w);
                    ah[s][i] = cv.s8;
                }
        } else {
            #pragma unroll
            for (int s = 0; s < 2; ++s)
                #pragma unroll
                for (int i = 0; i < 2; ++i) {
                    int rb = (i * 16 + ln) * 128;
                    int sw = (ln & 7) << 4;
                    ah[s][i] = *(const short8*)&sA[buf][rb + ((s * 64 + h * 16) ^ sw)];
                }
        }

        #pragma unroll
        for (int s = 0; s < 2; ++s)
            #pragma unroll
            for (int i = 0; i < 2; ++i)
                #pragma unroll
                for (int jj = 0; jj < 2; ++jj)
                    acc[i][jj] = __builtin_amdgcn_mfma_f32_16x16x32_bf16(
                        ah[s][i], bh[s][jj], acc[i][jj], 0, 0, 0);

        __syncthreads();
        buf ^= 1;
    }

    // epilogue: nontemporal stores (bypass L2 write path)
    #pragma unroll
    for (int i = 0; i < 2; ++i)
        #pragma unroll
        for (int v = 0; v < 4; ++v) {
            int gr = row0 + i * 16 + h * 4 + v;
            if (gr < M) {
                #pragma unroll
                for (int jj = 0; jj < 2; ++jj)
                    __builtin_nontemporal_store(
                        f2bf(acc[i][jj][v]),
                        &C[(size_t)gr * 128 + w * 32 + jj * 16 + ln]);
            }
        }
}

__global__ __launch_bounds__(256) void k_gemmL1(const void* __restrict__ Ap,
                                                const u16* __restrict__ Wh,
                                                u16* __restrict__ C, int M) {
    gemm_body<F_IN, true>(Ap, Wh, C, M);
}

__global__ __launch_bounds__(256) void k_gemmL2(const void* __restrict__ Ap,
                                                const u16* __restrict__ Wh,
                                                u16* __restrict__ C, int M) {
    gemm_body<HID, false>(Ap, Wh, C, M);
}

// ---------------- GEMM: [M x 128] bf16 @ [128 x 40] f32 -> [M x 40] bf16 -

__global__ void k_gemm40(const u16* __restrict__ A, const float* __restrict__ W,
                         u16* __restrict__ C, int M) {
    __shared__ float As[64][132];
    __shared__ float Ws[128][40];
    int t = threadIdx.x;
    int row0 = blockIdx.x * 64;
    #pragma unroll
    for (int i = 0; i < 4; ++i) {
        int fidx = t + i * 256;
        int r = fidx >> 4;
        int c = (fidx & 15) * 8;
        int gr = row0 + r;
        uint4 v = {0, 0, 0, 0};
        if (gr < M) v = *reinterpret_cast<const uint4*>(A + (size_t)gr * 128 + c);
        const u16* pv = (const u16*)&v;
        #pragma unroll
        for (int q = 0; q < 8; ++q) As[r][c + q] = bf2f(pv[q]);
    }
    #pragma unroll
    for (int i = 0; i < 5; ++i) {
        int fidx = t + i * 256;
        int r = fidx / 10, c = (fidx % 10) << 2;
        float4 v = *reinterpret_cast<const float4*>(W + r * 40 + c);
        *reinterpret_cast<float4*>(&Ws[r][c]) = v;
    }
    __syncthreads();
    int r = t >> 2;
    int cg = t & 3;
    float acc[10];
    #pragma unroll
    for (int j = 0; j < 10; ++j) acc[j] = 0.0f;
    for (int k = 0; k < 128; ++k) {
        float a = As[r][k];
        #pragma unroll
        for (int j = 0; j < 10; ++j)
            acc[j] = fmaf(a, Ws[k][cg * 10 + j], acc[j]);
    }
    int gr = row0 + r;
    if (gr < M) {
        // packed u32 NT stores (5 instead of 10 scalar u16)
        u16* base = C + (size_t)gr * 40 + cg * 10;
        #pragma unroll
        for (int j = 0; j < 5; ++j) {
            unsigned int p = (unsigned int)f2bf(acc[2 * j]) |
                             ((unsigned int)f2bf(acc[2 * j + 1]) << 16);
            __builtin_nontemporal_store(p, (unsigned int*)(base + 2 * j));
        }
    }
}

// ---------------- CSR aggregation, bf16 h -> relu'd bf16 out (NF=128) ---

__global__ void k_agg_csr_bf(const u16* __restrict__ h, const float* __restrict__ dinv,
                             const float* __restrict__ bias,
                             const int* __restrict__ rowptr, const int* __restrict__ csr_col,
                             const float* __restrict__ csr_nrm, u16* __restrict__ out) {
    int gid = blockIdx.x * 256 + threadIdx.x;
    if (gid >= N_NODES * 32) return;
    int i = gid >> 5;
    int q = (gid & 31) * 4;
    const u16* hq = h + q;
    float di = dinv[i];
    float s = di * di;
    ushort4 hv = *reinterpret_cast<const ushort4*>(hq + (size_t)i * 128);
    float4 bv = *reinterpret_cast<const float4*>(bias + q);
    float4 acc;
    acc.x = fmaf(bf2f(hv.x), s, bv.x);
    acc.y = fmaf(bf2f(hv.y), s, bv.y);
    acc.z = fmaf(bf2f(hv.z), s, bv.z);
    acc.w = fmaf(bf2f(hv.w), s, bv.w);
    int e = rowptr[i], e1 = rowptr[i + 1];
    for (; e + 4 <= e1; e += 4) {
        int c0 = csr_col[e], c1 = csr_col[e + 1], c2 = csr_col[e + 2], c3 = csr_col[e + 3];
        float n0 = csr_nrm[e], n1 = csr_nrm[e + 1], n2 = csr_nrm[e + 2], n3 = csr_nrm[e + 3];
        ushort4 v0 = *reinterpret_cast<const ushort4*>(hq + (size_t)c0 * 128);
        ushort4 v1 = *reinterpret_cast<const ushort4*>(hq + (size_t)c1 * 128);
        ushort4 v2 = *reinterpret_cast<const ushort4*>(hq + (size_t)c2 * 128);
        ushort4 v3 = *reinterpret_cast<const ushort4*>(hq + (size_t)c3 * 128);
        acc.x = fmaf(bf2f(v0.x), n0, acc.x);
        acc.y = fmaf(bf2f(v0.y), n0, acc.y);
        acc.z = fmaf(bf2f(v0.z), n0, acc.z);
        acc.w = fmaf(bf2f(v0.w), n0, acc.w);
        acc.x = fmaf(bf2f(v1.x), n1, acc.x);
        acc.y = fmaf(bf2f(v1.y), n1, acc.y);
        acc.z = fmaf(bf2f(v1.z), n1, acc.z);
        acc.w = fmaf(bf2f(v1.w), n1, acc.w);
        acc.x = fmaf(bf2f(v2.x), n2, acc.x);
        acc.y = fmaf(bf2f(v2.y), n2, acc.y);
        acc.z = fmaf(bf2f(v2.z), n2, acc.z);
        acc.w = fmaf(bf2f(v2.w), n2, acc.w);
        acc.x = fmaf(bf2f(v3.x), n3, acc.x);
        acc.y = fmaf(bf2f(v3.y), n3, acc.y);
        acc.z = fmaf(bf2f(v3.z), n3, acc.z);
        acc.w = fmaf(bf2f(v3.w), n3, acc.w);
    }
    for (; e < e1; ++e) {
        int c0 = csr_col[e];
        float n0 = csr_nrm[e];
        ushort4 v0 = *reinterpret_cast<const ushort4*>(hq + (size_t)c0 * 128);
        acc.x = fmaf(bf2f(v0.x), n0, acc.x);
        acc.y = fmaf(bf2f(v0.y), n0, acc.y);
        acc.z = fmaf(bf2f(v0.z), n0, acc.z);
        acc.w = fmaf(bf2f(v0.w), n0, acc.w);
    }
    ushort4 o;
    o.x = f2bf(fmaxf(acc.x, 0.f));
    o.y = f2bf(fmaxf(acc.y, 0.f));
    o.z = f2bf(fmaxf(acc.z, 0.f));
    o.w = f2bf(fmaxf(acc.w, 0.f));
    *reinterpret_cast<ushort4*>(out + (size_t)i * 128 + q) = o;
}

// ---------------- CSR aggregation, bf16 h (NF=40, layer 3) -> f32 out ---

__global__ void k_agg_csr40_bf(const u16* __restrict__ h, const float* __restrict__ dinv,
                               const float* __restrict__ bias,
                               const int* __restrict__ rowptr, const int* __restrict__ csr_col,
                               const float* __restrict__ csr_nrm, float* __restrict__ out) {
    const int TPN = 10;
    int gid = blockIdx.x * 256 + threadIdx.x;
    if (gid >= N_NODES * TPN) return;
    int i = gid / TPN;
    int q = (gid % TPN) * 4;
    const u16* hq = h + q;
    float di = dinv[i];
    float s = di * di;
    ushort4 hv = *reinterpret_cast<const ushort4*>(hq + (size_t)i * 40);
    float4 bv = *reinterpret_cast<const float4*>(bias + q);
    float4 acc;
    acc.x = fmaf(bf2f(hv.x), s, bv.x);
    acc.y = fmaf(bf2f(hv.y), s, bv.y);
    acc.z = fmaf(bf2f(hv.z), s, bv.z);
    acc.w = fmaf(bf2f(hv.w), s, bv.w);
    int e = rowptr[i], e1 = rowptr[i + 1];
    for (; e + 4 <= e1; e += 4) {
        int c0 = csr_col[e], c1 = csr_col[e + 1], c2 = csr_col[e + 2], c3 = csr_col[e + 3];
        float n0 = csr_nrm[e], n1 = csr_nrm[e + 1], n2 = csr_nrm[e + 2], n3 = csr_nrm[e + 3];
        ushort4 v0 = *reinterpret_cast<const ushort4*>(hq + (size_t)c0 * 40);
        ushort4 v1 = *reinterpret_cast<const ushort4*>(hq + (size_t)c1 * 40);
        ushort4 v2 = *reinterpret_cast<const ushort4*>(hq + (size_t)c2 * 40);
        ushort4 v3 = *reinterpret_cast<const ushort4*>(hq + (size_t)c3 * 40);
        acc.x = fmaf(bf2f(v0.x), n0, acc.x);
        acc.y = fmaf(bf2f(v0.y), n0, acc.y);
        acc.z = fmaf(bf2f(v0.z), n0, acc.z);
        acc.w = fmaf(bf2f(v0.w), n0, acc.w);
        acc.x = fmaf(bf2f(v1.x), n1, acc.x);
        acc.y = fmaf(bf2f(v1.y), n1, acc.y);
        acc.z = fmaf(bf2f(v1.z), n1, acc.z);
        acc.w = fmaf(bf2f(v1.w), n1, acc.w);
        acc.x = fmaf(bf2f(v2.x), n2, acc.x);
        acc.y = fmaf(bf2f(v2.y), n2, acc.y);
        acc.z = fmaf(bf2f(v2.z), n2, acc.z);
        acc.w = fmaf(bf2f(v2.w), n2, acc.w);
        acc.x = fmaf(bf2f(v3.x), n3, acc.x);
        acc.y = fmaf(bf2f(v3.y), n3, acc.y);
        acc.z = fmaf(bf2f(v3.z), n3, acc.z);
        acc.w = fmaf(bf2f(v3.w), n3, acc.w);
    }
    for (; e < e1; ++e) {
        int c0 = csr_col[e];
        float n0 = csr_nrm[e];
        ushort4 v0 = *reinterpret_cast<const ushort4*>(hq + (size_t)c0 * 40);
        acc.x = fmaf(bf2f(v0.x), n0, acc.x);
        acc.y = fmaf(bf2f(v0.y), n0, acc.y);
        acc.z = fmaf(bf2f(v0.z), n0, acc.z);
        acc.w = fmaf(bf2f(v0.w), n0, acc.w);
    }
    *reinterpret_cast<float4*>(out + (size_t)i * 40 + q) = acc;
}

// ---------------- log_softmax (in-place, one wave per row) ----------------

__global__ void k_logsoftmax(float* __restrict__ out) {
    int wave = threadIdx.x >> 6, lane = threadIdx.x & 63;
    int rowi = blockIdx.x * 4 + wave;
    if (rowi >= N_NODES) return;
    float v = (lane < NCLS) ? out[(size_t)rowi * NCLS + lane] : -INFINITY;
    float m = v;
    #pragma unroll
    for (int off = 32; off; off >>= 1) m = fmaxf(m, __shfl_xor(m, off));
    float ex = (lane < NCLS) ? expf(v - m) : 0.0f;
    float s = ex;
    #pragma unroll
    for (int off = 32; off; off >>= 1) s += __shfl_xor(s, off);
    float ls = logf(s);
    if (lane < NCLS) out[(size_t)rowi * NCLS + lane] = v - m - ls;
}

// ---------------- launch ----------------

extern "C" void kernel_launch(void* const* d_in, const int* in_sizes, int n_in,
                              void* d_out, int out_size, void* d_ws, size_t ws_size,
                              hipStream_t stream) {
    const float* x  = (const float*)d_in[0];
    const int* ei   = (const int*)d_in[1];
    const float* W1 = (const float*)d_in[2];
    const float* b1 = (const float*)d_in[3];
    const float* W2 = (const float*)d_in[4];
    const float* b2 = (const float*)d_in[5];
    const float* W3 = (const float*)d_in[6];
    const float* b3 = (const float*)d_in[7];
    float* out = (float*)d_out;

    const int* row = ei;             // targets
    const int* col = ei + N_EDGES;   // sources

    char* ws = (char*)d_ws;
    int*   deg      = (int*)ws;   ws += sizeof(int) * (size_t)N_NODES * PAD;
    int*   cursor   = (int*)ws;   ws += sizeof(int) * (size_t)N_NODES * PAD;
    int*   rowptr   = (int*)ws;   ws += sizeof(int) * 50004;
    int*   blocksum = (int*)ws;   ws += sizeof(int) * NBLK;
    int*   blockoff = (int*)ws;   ws += sizeof(int) * 204;
    int*   csr_col  = (int*)ws;   ws += sizeof(int) * N_EDGES;
    float* csr_nrm  = (float*)ws; ws += sizeof(float) * N_EDGES;
    float* dinv     = (float*)ws; ws += sizeof(float) * N_NODES;
    u16*   wt1hi    = (u16*)ws;   ws += sizeof(u16) * F_IN * 128;
    u16*   wt2hi    = (u16*)ws;   ws += sizeof(u16) * HID * 128;
    u16*   hbuf     = (u16*)ws;   ws += sizeof(u16) * (size_t)N_NODES * HID;
    u16*   abuf     = (u16*)ws;   ws += sizeof(u16) * (size_t)N_NODES * HID;
    u16*   h3       = (u16*)ws;   ws += sizeof(u16) * (size_t)N_NODES * NCLS;

    const int NB_N   = (N_NODES + 255) / 256;
    const int NB_G   = (N_NODES + 63) / 64;    // gemm40
    const int NB_G32 = (N_NODES + 31) / 32;    // 32-row gemm tiles
    const int NB_BIN = 2048;                   // 256 blocks per bin x 8 bins

    // weight split (fragment-major, once)
    k_wsplit<<<(F_IN * 128 + 255) / 256, 256, 0, stream>>>(W1, wt1hi, F_IN);
    k_wsplit<<<(HID * 128 + 255) / 256, 256, 0, stream>>>(W2, wt2hi, HID);

    // CSR build (once, shared by all 3 layers) — XCD-binned count/scatter
    k_zero_deg<<<NB_N, 256, 0, stream>>>(deg);
    k_count_bin<<<NB_BIN, 256, 0, stream>>>(row, deg);
    k_scan_partial<<<NBLK, 256, 0, stream>>>(deg, blocksum);
    k_scan_block<<<1, 256, 0, stream>>>(blocksum, blockoff);
    k_scan_final<<<NBLK, 256, 0, stream>>>(deg, blockoff, rowptr, cursor, dinv);
    k_scatter_bin<<<NB_BIN, 256, 0, stream>>>(row, col, dinv, cursor, csr_col, csr_nrm);

    // layer 1: x (f32) @ W1 -> hbuf (bf16)
    k_gemmL1<<<NB_G32, 256, 0, stream>>>(x, wt1hi, hbuf, N_NODES);
    k_agg_csr_bf<<<(N_NODES * 32 + 255) / 256, 256, 0, stream>>>(
        hbuf, dinv, b1, rowptr, csr_col, csr_nrm, abuf);   // -> relu'd bf16

    // layer 2: abuf (bf16) @ W2 -> hbuf (bf16)
    k_gemmL2<<<NB_G32, 256, 0, stream>>>(abuf, wt2hi, hbuf, N_NODES);
    k_agg_csr_bf<<<(N_NODES * 32 + 255) / 256, 256, 0, stream>>>(
        hbuf, dinv, b2, rowptr, csr_col, csr_nrm, abuf);   // -> relu'd bf16

    // layer 3: abuf (bf16) @ W3 -> h3 (bf16), agg -> f32 out, log_softmax
    k_gemm40<<<NB_G, 256, 0, stream>>>(abuf, W3, h3, N_NODES);
    k_agg_csr40_bf<<<(N_NODES * 10 + 255) / 256, 256, 0, stream>>>(
        h3, dinv, b3, rowptr, csr_col, csr_nrm, out);
    k_logsoftmax<<<(N_NODES + 3) / 4, 256, 0, stream>>>(out);
}